// Round 1
// baseline (859.228 us; speedup 1.0000x reference)
//
#include <hip/hip_runtime.h>
#include <hip/hip_bf16.h>

// BiLSTM-CRF fused pipeline for MI355X (gfx950).
// Stages: pack W_ih (bf16, K padded 300->320) | gather+pack emb rows (bf16)
//         | MFMA bf16 GEMM gx = emb @ W^T  (M=49152,N=1024,K=320)
//         | fused LSTM recurrence (both dirs) + W_fc feats projection
//         | CRF forward + gold score | mean reduce.

#define B_   256
#define T_   192
#define E_   300
#define KP   320   // padded K
#define H_   128
#define G4   512   // 4*H
#define NG   1024  // both directions
#define NT_  13
#define NEGV -10000.0f

typedef __attribute__((ext_vector_type(8))) short bf16x8;
typedef __attribute__((ext_vector_type(4))) float f32x4;

__device__ __forceinline__ unsigned short f2bf(float f) {
    unsigned u = __float_as_uint(f);
    unsigned r = (u + 0x7FFFu + ((u >> 16) & 1u)) >> 16;   // RNE
    return (unsigned short)r;
}
__device__ __forceinline__ float bf2f(unsigned short h) {
    return __uint_as_float(((unsigned)h) << 16);
}
__device__ __forceinline__ float sigf(float x) { return 1.0f / (1.0f + __expf(-x)); }
__device__ __forceinline__ float tanhfast(float x) { return 2.0f / (1.0f + __expf(-2.0f * x)) - 1.0f; }

// ---------------- pack W_ih (concat f,b) into bf16 [1024][320] ----------------
__global__ void pack_w_kernel(const float* __restrict__ Wf, const float* __restrict__ Wb,
                              unsigned short* __restrict__ Wp) {
    int g = blockIdx.x;          // 0..1023
    int k = threadIdx.x;         // 0..319
    float v = 0.0f;
    if (k < E_) v = (g < G4) ? Wf[g * E_ + k] : Wb[(g - G4) * E_ + k];
    Wp[g * KP + k] = f2bf(v);
}

// ---------------- gather + pack embedding rows into bf16 [49152][320] --------
__global__ void pack_emb_kernel(const float* __restrict__ emb, const int* __restrict__ sent,
                                unsigned short* __restrict__ A) {
    int m = blockIdx.x;          // 0..49151
    int k = threadIdx.x;         // 0..319
    int tok = sent[m];
    float v = 0.0f;
    if (k < E_) v = emb[(size_t)tok * E_ + k];
    A[(size_t)m * KP + k] = f2bf(v);
}

// ---------------- bf16 MFMA GEMM: C[m][n] = sum_k A[m][k] * W[n][k] ----------
__global__ __launch_bounds__(256, 2) void gemm_kernel(const unsigned short* __restrict__ A,
                                                      const unsigned short* __restrict__ Bw,
                                                      unsigned short* __restrict__ C) {
    __shared__ __align__(16) unsigned short As[128 * 64];
    __shared__ __align__(16) unsigned short Bs[128 * 64];
    const int tid  = threadIdx.x;
    const int lane = tid & 63;
    const int wave = tid >> 6;
    const int wr = wave >> 1, wc = wave & 1;
    const int mBase = blockIdx.y * 128;
    const int nBase = blockIdx.x * 128;
    f32x4 acc[4][4] = {};
    for (int k0 = 0; k0 < KP; k0 += 64) {
        #pragma unroll
        for (int j = 0; j < 4; j++) {
            int c   = tid + 256 * j;       // 16B chunk id 0..1023
            int row = c >> 3;
            int col = (c & 7) * 8;
            *(uint4*)(As + row * 64 + col) = *(const uint4*)(A  + (size_t)(mBase + row) * KP + k0 + col);
            *(uint4*)(Bs + row * 64 + col) = *(const uint4*)(Bw + (size_t)(nBase + row) * KP + k0 + col);
        }
        __syncthreads();
        #pragma unroll
        for (int ks = 0; ks < 2; ks++) {
            bf16x8 af[4], bfr[4];
            #pragma unroll
            for (int i = 0; i < 4; i++) {
                int arow = wr * 64 + i * 16 + (lane & 15);
                af[i]  = *(const bf16x8*)(As + arow * 64 + ks * 32 + (lane >> 4) * 8);
                int brow = wc * 64 + i * 16 + (lane & 15);
                bfr[i] = *(const bf16x8*)(Bs + brow * 64 + ks * 32 + (lane >> 4) * 8);
            }
            #pragma unroll
            for (int i = 0; i < 4; i++)
                #pragma unroll
                for (int n2 = 0; n2 < 4; n2++)
                    acc[i][n2] = __builtin_amdgcn_mfma_f32_16x16x32_bf16(af[i], bfr[n2], acc[i][n2], 0, 0, 0);
        }
        __syncthreads();
    }
    #pragma unroll
    for (int i = 0; i < 4; i++)
        #pragma unroll
        for (int n2 = 0; n2 < 4; n2++)
            #pragma unroll
            for (int r = 0; r < 4; r++) {
                int row = mBase + wr * 64 + i  * 16 + (lane >> 4) * 4 + r;
                int col = nBase + wc * 64 + n2 * 16 + (lane & 15);
                C[(size_t)row * NG + col] = f2bf(acc[i][n2][r]);
            }
}

// ---------------- fused LSTM recurrence + feats projection -------------------
// grid 256: block = (dir, batch pair). 576 threads: 512 gate threads (W_hh row
// in registers), 64 feats threads (compute W_fc . h(s-1) overlapped with gates).
__global__ __launch_bounds__(576, 3) void lstm_kernel(const unsigned short* __restrict__ gx,
                                                      const float* __restrict__ Whf,
                                                      const float* __restrict__ Whb,
                                                      const float* __restrict__ bf_,
                                                      const float* __restrict__ bb_,
                                                      const int* __restrict__ seq_len,
                                                      const float* __restrict__ Wfc,
                                                      float* __restrict__ featsF,
                                                      float* __restrict__ featsB) {
    __shared__ __align__(16) float hs[2][H_];
    __shared__ float gbuf[2][G4];
    __shared__ __align__(16) float WfcL[NT_ * 132];
    const int tid = threadIdx.x;
    const int dir = blockIdx.x & 1;
    const int b0  = (blockIdx.x >> 1) * 2;
    const float* Whh  = dir ? Whb : Whf;
    const float* bias = dir ? bb_ : bf_;
    float* fOut = dir ? featsB : featsF;

    int L0 = min(max(seq_len[b0], 1), T_);
    int L1 = min(max(seq_len[b0 + 1], 1), T_);
    const int maxL = max(L0, L1);

    // load W_fc half for this dir into LDS (padded stride 132)
    for (int idx = tid; idx < NT_ * H_; idx += 576) {
        int n = idx >> 7, k = idx & 127;
        WfcL[n * 132 + k] = Wfc[n * 256 + dir * H_ + k];
    }
    if (tid < 256) hs[tid >> 7][tid & 127] = 0.0f;

    float W[H_];
    float bg = 0.0f;
    if (tid < G4) {
        const float4* w4 = (const float4*)(Whh + (size_t)tid * H_);
        #pragma unroll
        for (int k4 = 0; k4 < 32; k4++) {
            float4 v = w4[k4];
            W[4 * k4] = v.x; W[4 * k4 + 1] = v.y; W[4 * k4 + 2] = v.z; W[4 * k4 + 3] = v.w;
        }
        bg = bias[tid];
    }
    float c0 = 0.0f, c1 = 0.0f;
    __syncthreads();

    for (int s = 0; s <= maxL; s++) {
        if (tid < G4) {
            // gates phase: g = gx + b + W_hh . h(s-1)
            #pragma unroll
            for (int r = 0; r < 2; r++) {
                int Lr = r ? L1 : L0;
                if (s < Lr) {
                    int pos = dir ? (Lr - 1 - s) : s;
                    float a0 = bg + bf2f(gx[((size_t)(b0 + r) * T_ + pos) * NG + dir * G4 + tid]);
                    const float4* h4 = (const float4*)&hs[r][0];
                    #pragma unroll
                    for (int k4 = 0; k4 < 32; k4++) {
                        float4 hv = h4[k4];
                        a0 += W[4 * k4] * hv.x + W[4 * k4 + 1] * hv.y
                            + W[4 * k4 + 2] * hv.z + W[4 * k4 + 3] * hv.w;
                    }
                    gbuf[r][tid] = a0;
                }
            }
        } else {
            // feats phase for step s-1 (h(s-1) is still live in hs)
            int p = tid - G4;
            if (p < 2 * NT_ && s > 0) {
                int r = p / NT_, n = p % NT_;
                int Lr = r ? L1 : L0;
                if (s - 1 < Lr) {
                    int pp = dir ? (Lr - s) : (s - 1);
                    const float4* wf4 = (const float4*)&WfcL[n * 132];
                    const float4* h4  = (const float4*)&hs[r][0];
                    float acc = 0.0f;
                    #pragma unroll
                    for (int k4 = 0; k4 < 32; k4++) {
                        float4 a = wf4[k4], hv = h4[k4];
                        acc += a.x * hv.x + a.y * hv.y + a.z * hv.z + a.w * hv.w;
                    }
                    fOut[((size_t)(b0 + r) * T_ + pp) * NT_ + n] = acc;
                }
            }
        }
        __syncthreads();
        if (tid < H_) {
            #pragma unroll
            for (int r = 0; r < 2; r++) {
                int Lr = r ? L1 : L0;
                if (s < Lr) {
                    float iv = sigf(gbuf[r][tid]);
                    float fv = sigf(gbuf[r][H_ + tid]);
                    float gv = tanhfast(gbuf[r][2 * H_ + tid]);
                    float ov = sigf(gbuf[r][3 * H_ + tid]);
                    float cn = fv * (r ? c1 : c0) + iv * gv;
                    if (r) c1 = cn; else c0 = cn;
                    hs[r][tid] = ov * tanhfast(cn);
                }
            }
        }
        __syncthreads();
    }
}

// ---------------- CRF forward + gold, per-batch nll --------------------------
__global__ __launch_bounds__(256) void crf_kernel(const float* __restrict__ fF,
                                                  const float* __restrict__ fB,
                                                  const float* __restrict__ bfc,
                                                  const float* __restrict__ trans,
                                                  const int* __restrict__ tags,
                                                  const int* __restrict__ seq_len,
                                                  float* __restrict__ nll) {
    __shared__ float Tl[NT_][16];
    __shared__ float al[2][16][16];
    __shared__ float red[16][16];
    __shared__ float gred[16][16];
    const int tid = threadIdx.x;
    const int sub = tid >> 4, j = tid & 15;
    const int b = blockIdx.x * 16 + sub;
    for (int idx = tid; idx < NT_ * NT_; idx += 256) Tl[idx / NT_][idx % NT_] = trans[idx];
    float bj = 0.0f;
    if (j < NT_) { al[0][sub][j] = (j == 0) ? 0.0f : NEGV; bj = bfc[j]; }
    const int Lb = min(max(seq_len[b], 1), T_);
    const float* fFb = fF + (size_t)b * T_ * NT_;
    const float* fBb = fB + (size_t)b * T_ * NT_;
    __syncthreads();
    int cu = 0;
    for (int t = 0; t < T_; t++) {
        if (j < NT_) {
            float feat = bj;
            if (t < Lb) feat += fFb[t * NT_ + j] + fBb[t * NT_ + j];
            float m = -3.0e38f;
            #pragma unroll
            for (int i = 0; i < NT_; i++) m = fmaxf(m, al[cu][sub][i] + Tl[j][i]);
            float ss = 0.0f;
            #pragma unroll
            for (int i = 0; i < NT_; i++) ss += __expf(al[cu][sub][i] + Tl[j][i] - m);
            al[cu ^ 1][sub][j] = m + __logf(ss) + feat;
        }
        __syncthreads();
        cu ^= 1;
    }
    if (j < NT_) red[sub][j] = al[cu][sub][j] + Tl[10][j];   // + trans[STOP][j]
    // gold partials
    float gp = 0.0f;
    if (j < NT_) {
        const int* tg = tags + (size_t)b * T_;
        for (int t = j; t < T_; t += NT_) {
            int tt = tg[t];
            int pv = (t == 0) ? 0 : tg[t - 1];
            float e = bfc[tt];
            if (t < Lb) e += fFb[t * NT_ + tt] + fBb[t * NT_ + tt];
            gp += Tl[tt][pv] + e;
        }
    }
    gred[sub][j] = gp;
    __syncthreads();
    if (j == 0) {
        float m = red[sub][0];
        #pragma unroll
        for (int i = 1; i < NT_; i++) m = fmaxf(m, red[sub][i]);
        float ss = 0.0f;
        #pragma unroll
        for (int i = 0; i < NT_; i++) ss += __expf(red[sub][i] - m);
        float fwd = m + __logf(ss);
        float gold = 0.0f;
        for (int i = 0; i < NT_; i++) gold += gred[sub][i];
        gold += Tl[10][tags[(size_t)b * T_ + (T_ - 1)]];
        nll[b] = fwd - gold;
    }
}

__global__ void reduce_mean_kernel(const float* __restrict__ nll, float* __restrict__ out) {
    int tid = threadIdx.x;
    float v = nll[tid];
    for (int o = 32; o > 0; o >>= 1) v += __shfl_down(v, o, 64);
    __shared__ float wsum[4];
    if ((tid & 63) == 0) wsum[tid >> 6] = v;
    __syncthreads();
    if (tid == 0) out[0] = (wsum[0] + wsum[1] + wsum[2] + wsum[3]) * (1.0f / 256.0f);
}

extern "C" void kernel_launch(void* const* d_in, const int* in_sizes, int n_in,
                              void* d_out, int out_size, void* d_ws, size_t ws_size,
                              hipStream_t stream) {
    const int*   sentence  = (const int*)d_in[0];
    const int*   seq_len   = (const int*)d_in[1];
    const int*   tags      = (const int*)d_in[2];
    const float* embedding = (const float*)d_in[3];
    const float* W_ih_f    = (const float*)d_in[4];
    const float* W_hh_f    = (const float*)d_in[5];
    const float* b_f       = (const float*)d_in[6];
    const float* W_ih_b    = (const float*)d_in[7];
    const float* W_hh_b    = (const float*)d_in[8];
    const float* b_b       = (const float*)d_in[9];
    const float* W_fc      = (const float*)d_in[10];
    const float* b_fc      = (const float*)d_in[11];
    const float* trans     = (const float*)d_in[12];
    float* out = (float*)d_out;

    char* ws = (char*)d_ws;
    const size_t M = (size_t)B_ * T_;                   // 49152
    unsigned short* Wp    = (unsigned short*)(ws);                       // 1024*320*2 = 655360
    unsigned short* Ap    = (unsigned short*)(ws + 655360);              // 49152*320*2 = 31457280
    unsigned short* gx    = (unsigned short*)(ws + 655360 + 31457280);   // 49152*1024*2 = 100663296
    float* featsF = (float*)(ws + 655360 + 31457280 + 100663296);        // 49152*13*4 = 2555904
    float* featsB = (float*)(ws + 655360 + 31457280 + 100663296 + 2555904);
    float* nll    = (float*)(ws + 655360 + 31457280 + 100663296 + 2 * 2555904);

    pack_w_kernel<<<NG, KP, 0, stream>>>(W_ih_f, W_ih_b, Wp);
    pack_emb_kernel<<<(int)M, KP, 0, stream>>>(embedding, sentence, Ap);
    dim3 gg(NG / 128, (int)(M / 128));
    gemm_kernel<<<gg, 256, 0, stream>>>(Ap, Wp, gx);
    lstm_kernel<<<B_, 576, 0, stream>>>(gx, W_hh_f, W_hh_b, b_f, b_b, seq_len, W_fc, featsF, featsB);
    crf_kernel<<<B_ / 16, 256, 0, stream>>>(featsF, featsB, b_fc, trans, tags, seq_len, nll);
    reduce_mean_kernel<<<1, 256, 0, stream>>>(nll, out);
}

// Round 2
// 818.303 us; speedup vs baseline: 1.0500x; 1.0500x over previous
//
#include <hip/hip_runtime.h>
#include <hip/hip_bf16.h>

// BiLSTM-CRF fused pipeline for MI355X (gfx950).
// R2: MFMA-based LSTM recurrence. W_hh lives in registers as MFMA B-frags
// (one block = one dir x 16 batch rows); h round-trips through a 4.4KB LDS
// buffer for A-frag re-layout; gx is emitted by the GEMM epilogue directly in
// per-lane dwordx4 order and software-prefetched one step ahead; a 5th wave
// computes the W_fc feats projection of step s-1 via MFMA, overlapped.

#define B_   256
#define T_   192
#define E_   300
#define KP   320   // padded K
#define H_   128
#define G4   512   // 4*H
#define NG   1024  // both directions
#define NT_  13
#define NEGV -10000.0f

typedef __attribute__((ext_vector_type(8))) short bf16x8;
typedef __attribute__((ext_vector_type(4))) float f32x4;

__device__ __forceinline__ unsigned short f2bf(float f) {
    unsigned u = __float_as_uint(f);
    unsigned r = (u + 0x7FFFu + ((u >> 16) & 1u)) >> 16;   // RNE
    return (unsigned short)r;
}
__device__ __forceinline__ float bf2f(unsigned short h) {
    return __uint_as_float(((unsigned)h) << 16);
}
__device__ __forceinline__ float sigf(float x) { return 1.0f / (1.0f + __expf(-x)); }
__device__ __forceinline__ float tanhfast(float x) { return 2.0f / (1.0f + __expf(-2.0f * x)) - 1.0f; }

// ---------------- pack W_ih (concat f,b) into bf16 [1024][320] ----------------
__global__ void pack_w_kernel(const float* __restrict__ Wf, const float* __restrict__ Wb,
                              unsigned short* __restrict__ Wp) {
    int g = blockIdx.x;          // 0..1023
    int k = threadIdx.x;         // 0..319
    float v = 0.0f;
    if (k < E_) v = (g < G4) ? Wf[g * E_ + k] : Wb[(g - G4) * E_ + k];
    Wp[g * KP + k] = f2bf(v);
}

// ---------------- gather + pack embedding rows into bf16 [49152][320] --------
__global__ void pack_emb_kernel(const float* __restrict__ emb, const int* __restrict__ sent,
                                unsigned short* __restrict__ A) {
    int m = blockIdx.x;          // 0..49151
    int k = threadIdx.x;         // 0..319
    int tok = sent[m];
    float v = 0.0f;
    if (k < E_) v = emb[(size_t)tok * E_ + k];
    A[(size_t)m * KP + k] = f2bf(v);
}

// ---------------- bf16 MFMA GEMM: gx = emb @ W^T, permuted epilogue ----------
// Output layout (per row of 1024 gates): [d:2][w:4][col:16][j:8] where the
// LSTM lane (wave w, lane&15=col) reads its 8 gates {t(j)*16+col} as one
// dwordx4; t(j) = 2w + (j&1) + 8*(j>>1).
__global__ __launch_bounds__(256, 2) void gemm_kernel(const unsigned short* __restrict__ A,
                                                      const unsigned short* __restrict__ Bw,
                                                      unsigned short* __restrict__ C) {
    __shared__ __align__(16) unsigned short As[128 * 64];
    __shared__ __align__(16) unsigned short Bs[128 * 64];
    const int tid  = threadIdx.x;
    const int lane = tid & 63;
    const int wave = tid >> 6;
    const int wr = wave >> 1, wc = wave & 1;
    const int mBase = blockIdx.y * 128;
    const int nBase = blockIdx.x * 128;
    f32x4 acc[4][4] = {};
    for (int k0 = 0; k0 < KP; k0 += 64) {
        #pragma unroll
        for (int j = 0; j < 4; j++) {
            int c   = tid + 256 * j;       // 16B chunk id 0..1023
            int row = c >> 3;
            int col = (c & 7) * 8;
            *(uint4*)(As + row * 64 + col) = *(const uint4*)(A  + (size_t)(mBase + row) * KP + k0 + col);
            *(uint4*)(Bs + row * 64 + col) = *(const uint4*)(Bw + (size_t)(nBase + row) * KP + k0 + col);
        }
        __syncthreads();
        #pragma unroll
        for (int ks = 0; ks < 2; ks++) {
            bf16x8 af[4], bfr[4];
            #pragma unroll
            for (int i = 0; i < 4; i++) {
                int arow = wr * 64 + i * 16 + (lane & 15);
                af[i]  = *(const bf16x8*)(As + arow * 64 + ks * 32 + (lane >> 4) * 8);
                int brow = wc * 64 + i * 16 + (lane & 15);
                bfr[i] = *(const bf16x8*)(Bs + brow * 64 + ks * 32 + (lane >> 4) * 8);
            }
            #pragma unroll
            for (int i = 0; i < 4; i++)
                #pragma unroll
                for (int n2 = 0; n2 < 4; n2++)
                    acc[i][n2] = __builtin_amdgcn_mfma_f32_16x16x32_bf16(af[i], bfr[n2], acc[i][n2], 0, 0, 0);
        }
        __syncthreads();
    }
    #pragma unroll
    for (int i = 0; i < 4; i++)
        #pragma unroll
        for (int r = 0; r < 4; r++) {
            int row = mBase + wr * 64 + i * 16 + (lane >> 4) * 4 + r;
            #pragma unroll
            for (int n2 = 0; n2 < 4; n2 += 2) {
                int n = nBase + wc * 64 + n2 * 16 + (lane & 15);
                int d  = n >> 9;
                int nd = n & 511;
                int t  = nd >> 4;            // even
                int cc = nd & 15;
                int w  = (t & 7) >> 1;
                int j  = ((t >> 3) << 1) | (t & 1);
                ushort2 v;
                v.x = f2bf(acc[i][n2][r]);
                v.y = f2bf(acc[i][n2 + 1][r]);
                *(ushort2*)(C + (size_t)row * NG + d * G4 + w * 128 + cc * 8 + j) = v;
            }
        }
}

// ---------------- MFMA LSTM recurrence + feats projection --------------------
// grid 32: block = (16 batch rows, dir). 320 threads = 5 waves.
// Waves 0-3: gates via MFMA (W_hh B-frags resident in VGPRs), activations,
//            c-state in registers, h -> LDS (bf16, stride 136).
// Wave 4:    feats(s-1) = Wfc_dir . h(s-1) via MFMA on the shared A-frags.
__global__ __launch_bounds__(320, 1) void lstm_kernel(const unsigned short* __restrict__ gxP,
                                                      const float* __restrict__ Whf,
                                                      const float* __restrict__ Whb,
                                                      const float* __restrict__ bf_,
                                                      const float* __restrict__ bb_,
                                                      const int* __restrict__ seq_len,
                                                      const float* __restrict__ Wfc,
                                                      float* __restrict__ featsF,
                                                      float* __restrict__ featsB) {
    __shared__ __align__(16) unsigned short hL[16 * 136];
    __shared__ int Ls[16];
    __shared__ int maxLs;
    const int tid  = threadIdx.x;
    const int wave = tid >> 6;
    const int lane = tid & 63;
    const int col  = lane & 15;
    const int quad = lane >> 4;
    const int dir  = blockIdx.x & 1;
    const int b0   = (blockIdx.x >> 1) * 16;
    const float* Whh  = dir ? Whb : Whf;
    const float* bias = dir ? bb_ : bf_;
    float* fOut = dir ? featsB : featsF;

    if (tid < 16) Ls[tid] = min(max(seq_len[b0 + tid], 1), T_);
    __syncthreads();
    if (tid == 0) { int m = 0; for (int i = 0; i < 16; i++) m = max(m, Ls[i]); maxLs = m; }
    __syncthreads();
    const int maxL = maxLs;
    int Lm[4];
    #pragma unroll
    for (int r = 0; r < 4; r++) Lm[r] = Ls[quad * 4 + r];

    bf16x8 Bf[8][4];          // W_hh fragments, resident all steps (waves 0-3)
    float  biasv[8];
    bf16x8 Wf4[4];            // W_fc fragments (wave 4)
    uint4  gxv[4];            // prefetched gx for current step (waves 0-3)
    if (wave < 4) {
        #pragma unroll
        for (int j = 0; j < 8; j++) {
            int t    = 2 * wave + (j & 1) + 8 * (j >> 1);
            int gate = t * 16 + col;
            biasv[j] = bias[gate];
            #pragma unroll
            for (int kc = 0; kc < 4; kc++) {
                const float* src = Whh + (size_t)gate * H_ + kc * 32 + quad * 8;
                #pragma unroll
                for (int e = 0; e < 8; e++) Bf[j][kc][e] = (short)f2bf(src[e]);
            }
        }
        #pragma unroll
        for (int r = 0; r < 4; r++) {
            int pos = dir ? (Lm[r] - 1) : 0;   // Lm >= 1 always
            gxv[r] = *(const uint4*)(gxP + ((size_t)((b0 + quad * 4 + r) * T_ + pos)) * NG
                                         + dir * G4 + wave * 128 + col * 8);
        }
    } else {
        #pragma unroll
        for (int kc = 0; kc < 4; kc++) {
            #pragma unroll
            for (int e = 0; e < 8; e++) {
                float v = (col < NT_) ? Wfc[col * 256 + dir * H_ + kc * 32 + quad * 8 + e] : 0.0f;
                Wf4[kc][e] = (short)f2bf(v);
            }
        }
    }

    float c01[2][4];
    #pragma unroll
    for (int u = 0; u < 2; u++)
        #pragma unroll
        for (int r = 0; r < 4; r++) c01[u][r] = 0.0f;
    bf16x8 Af[4];
    #pragma unroll
    for (int kc = 0; kc < 4; kc++)
        #pragma unroll
        for (int e = 0; e < 8; e++) Af[kc][e] = 0;   // h(-1) = 0

    for (int s = 0; s <= maxL; s++) {
        if (wave < 4) {
            if (s < maxL) {
                uint4 cur[4];
                #pragma unroll
                for (int r = 0; r < 4; r++) cur[r] = gxv[r];
                // prefetch gx for step s+1
                #pragma unroll
                for (int r = 0; r < 4; r++) {
                    if (s + 1 < Lm[r]) {
                        int pos = dir ? (Lm[r] - 2 - s) : (s + 1);
                        gxv[r] = *(const uint4*)(gxP + ((size_t)((b0 + quad * 4 + r) * T_ + pos)) * NG
                                                     + dir * G4 + wave * 128 + col * 8);
                    }
                }
                f32x4 acc[8];
                #pragma unroll
                for (int j = 0; j < 8; j++) acc[j] = (f32x4){0.f, 0.f, 0.f, 0.f};
                #pragma unroll
                for (int kc = 0; kc < 4; kc++)
                    #pragma unroll
                    for (int j = 0; j < 8; j++)
                        acc[j] = __builtin_amdgcn_mfma_f32_16x16x32_bf16(Af[kc], Bf[j][kc], acc[j], 0, 0, 0);
                #pragma unroll
                for (int r = 0; r < 4; r++) {
                    if (s < Lm[r]) {
                        const unsigned short* gp = (const unsigned short*)&cur[r];
                        #pragma unroll
                        for (int u = 0; u < 2; u++) {
                            float iv = acc[0 + u][r] + bf2f(gp[0 + u]) + biasv[0 + u];
                            float fv = acc[2 + u][r] + bf2f(gp[2 + u]) + biasv[2 + u];
                            float gv = acc[4 + u][r] + bf2f(gp[4 + u]) + biasv[4 + u];
                            float ov = acc[6 + u][r] + bf2f(gp[6 + u]) + biasv[6 + u];
                            float cn = sigf(fv) * c01[u][r] + sigf(iv) * tanhfast(gv);
                            c01[u][r] = cn;
                            float hn = sigf(ov) * tanhfast(cn);
                            hL[(quad * 4 + r) * 136 + 32 * wave + 16 * u + col] = f2bf(hn);
                        }
                    }
                }
            }
        } else {
            if (s >= 1) {
                f32x4 fc = (f32x4){0.f, 0.f, 0.f, 0.f};
                #pragma unroll
                for (int kc = 0; kc < 4; kc++)
                    fc = __builtin_amdgcn_mfma_f32_16x16x32_bf16(Af[kc], Wf4[kc], fc, 0, 0, 0);
                if (col < NT_) {
                    #pragma unroll
                    for (int r = 0; r < 4; r++) {
                        if (s - 1 < Lm[r]) {
                            int pos = dir ? (Lm[r] - s) : (s - 1);
                            fOut[((size_t)(b0 + quad * 4 + r) * T_ + pos) * NT_ + col] = fc[r];
                        }
                    }
                }
            }
        }
        __syncthreads();
        if (s < maxL) {
            #pragma unroll
            for (int kc = 0; kc < 4; kc++)
                Af[kc] = *(const bf16x8*)(hL + col * 136 + kc * 32 + quad * 8);
        }
        __syncthreads();
    }
}

// ---------------- CRF forward + gold, per-batch nll --------------------------
__global__ __launch_bounds__(256) void crf_kernel(const float* __restrict__ fF,
                                                  const float* __restrict__ fB,
                                                  const float* __restrict__ bfc,
                                                  const float* __restrict__ trans,
                                                  const int* __restrict__ tags,
                                                  const int* __restrict__ seq_len,
                                                  float* __restrict__ nll) {
    __shared__ float Tl[NT_][16];
    __shared__ float al[2][16][16];
    __shared__ float red[16][16];
    __shared__ float gred[16][16];
    const int tid = threadIdx.x;
    const int sub = tid >> 4, j = tid & 15;
    const int b = blockIdx.x * 16 + sub;
    for (int idx = tid; idx < NT_ * NT_; idx += 256) Tl[idx / NT_][idx % NT_] = trans[idx];
    float bj = 0.0f;
    if (j < NT_) { al[0][sub][j] = (j == 0) ? 0.0f : NEGV; bj = bfc[j]; }
    const int Lb = min(max(seq_len[b], 1), T_);
    const float* fFb = fF + (size_t)b * T_ * NT_;
    const float* fBb = fB + (size_t)b * T_ * NT_;
    __syncthreads();
    int cu = 0;
    for (int t = 0; t < T_; t++) {
        if (j < NT_) {
            float feat = bj;
            if (t < Lb) feat += fFb[t * NT_ + j] + fBb[t * NT_ + j];
            float m = -3.0e38f;
            #pragma unroll
            for (int i = 0; i < NT_; i++) m = fmaxf(m, al[cu][sub][i] + Tl[j][i]);
            float ss = 0.0f;
            #pragma unroll
            for (int i = 0; i < NT_; i++) ss += __expf(al[cu][sub][i] + Tl[j][i] - m);
            al[cu ^ 1][sub][j] = m + __logf(ss) + feat;
        }
        __syncthreads();
        cu ^= 1;
    }
    if (j < NT_) red[sub][j] = al[cu][sub][j] + Tl[10][j];   // + trans[STOP][j]
    // gold partials
    float gp = 0.0f;
    if (j < NT_) {
        const int* tg = tags + (size_t)b * T_;
        for (int t = j; t < T_; t += NT_) {
            int tt = tg[t];
            int pv = (t == 0) ? 0 : tg[t - 1];
            float e = bfc[tt];
            if (t < Lb) e += fFb[t * NT_ + tt] + fBb[t * NT_ + tt];
            gp += Tl[tt][pv] + e;
        }
    }
    gred[sub][j] = gp;
    __syncthreads();
    if (j == 0) {
        float m = red[sub][0];
        #pragma unroll
        for (int i = 1; i < NT_; i++) m = fmaxf(m, red[sub][i]);
        float ss = 0.0f;
        #pragma unroll
        for (int i = 0; i < NT_; i++) ss += __expf(red[sub][i] - m);
        float fwd = m + __logf(ss);
        float gold = 0.0f;
        for (int i = 0; i < NT_; i++) gold += gred[sub][i];
        gold += Tl[10][tags[(size_t)b * T_ + (T_ - 1)]];
        nll[b] = fwd - gold;
    }
}

__global__ void reduce_mean_kernel(const float* __restrict__ nll, float* __restrict__ out) {
    int tid = threadIdx.x;
    float v = nll[tid];
    for (int o = 32; o > 0; o >>= 1) v += __shfl_down(v, o, 64);
    __shared__ float wsum[4];
    if ((tid & 63) == 0) wsum[tid >> 6] = v;
    __syncthreads();
    if (tid == 0) out[0] = (wsum[0] + wsum[1] + wsum[2] + wsum[3]) * (1.0f / 256.0f);
}

extern "C" void kernel_launch(void* const* d_in, const int* in_sizes, int n_in,
                              void* d_out, int out_size, void* d_ws, size_t ws_size,
                              hipStream_t stream) {
    const int*   sentence  = (const int*)d_in[0];
    const int*   seq_len   = (const int*)d_in[1];
    const int*   tags      = (const int*)d_in[2];
    const float* embedding = (const float*)d_in[3];
    const float* W_ih_f    = (const float*)d_in[4];
    const float* W_hh_f    = (const float*)d_in[5];
    const float* b_f       = (const float*)d_in[6];
    const float* W_ih_b    = (const float*)d_in[7];
    const float* W_hh_b    = (const float*)d_in[8];
    const float* b_b       = (const float*)d_in[9];
    const float* W_fc      = (const float*)d_in[10];
    const float* b_fc      = (const float*)d_in[11];
    const float* trans     = (const float*)d_in[12];
    float* out = (float*)d_out;

    char* ws = (char*)d_ws;
    const size_t M = (size_t)B_ * T_;                   // 49152
    unsigned short* Wp    = (unsigned short*)(ws);                       // 1024*320*2 = 655360
    unsigned short* Ap    = (unsigned short*)(ws + 655360);              // 49152*320*2 = 31457280
    unsigned short* gx    = (unsigned short*)(ws + 655360 + 31457280);   // 49152*1024*2 = 100663296
    float* featsF = (float*)(ws + 655360 + 31457280 + 100663296);        // 49152*13*4 = 2555904
    float* featsB = (float*)(ws + 655360 + 31457280 + 100663296 + 2555904);
    float* nll    = (float*)(ws + 655360 + 31457280 + 100663296 + 2 * 2555904);

    pack_w_kernel<<<NG, KP, 0, stream>>>(W_ih_f, W_ih_b, Wp);
    pack_emb_kernel<<<(int)M, KP, 0, stream>>>(embedding, sentence, Ap);
    dim3 gg(NG / 128, (int)(M / 128));
    gemm_kernel<<<gg, 256, 0, stream>>>(Ap, Wp, gx);
    lstm_kernel<<<32, 320, 0, stream>>>(gx, W_hh_f, W_hh_b, b_f, b_b, seq_len, W_fc, featsF, featsB);
    crf_kernel<<<B_ / 16, 256, 0, stream>>>(featsF, featsB, b_fc, trans, tags, seq_len, nll);
    reduce_mean_kernel<<<1, 256, 0, stream>>>(nll, out);
}

// Round 3
// 693.038 us; speedup vs baseline: 1.2398x; 1.1807x over previous
//
#include <hip/hip_runtime.h>
#include <hip/hip_bf16.h>

// BiLSTM-CRF fused pipeline for MI355X (gfx950).
// R3: 8 gate waves (Bf=64 VGPR/wave, no spill), bias folded into GEMM
// epilogue, gx seeds the MFMA C operand, GEMM N-tiling permuted so each
// wave's 4 acc groups = 4 gate types of one unit group (ushort4 stores /
// ushort4 LSTM loads), hL stride 144 (16B aligned, fewer bank conflicts).

#define B_   256
#define T_   192
#define E_   300
#define KP   320   // padded K
#define H_   128
#define G4   512   // 4*H
#define NG   1024  // both directions
#define NT_  13
#define NEGV -10000.0f
#define HSTR 144   // hL row stride in ushorts (288B, 16B-aligned)

typedef __attribute__((ext_vector_type(8))) short bf16x8;
typedef __attribute__((ext_vector_type(4))) float f32x4;
typedef __attribute__((ext_vector_type(4))) unsigned short u16x4;

__device__ __forceinline__ unsigned short f2bf(float f) {
    unsigned u = __float_as_uint(f);
    unsigned r = (u + 0x7FFFu + ((u >> 16) & 1u)) >> 16;   // RNE
    return (unsigned short)r;
}
__device__ __forceinline__ float bf2f(unsigned short h) {
    return __uint_as_float(((unsigned)h) << 16);
}
__device__ __forceinline__ float sigf(float x) { return 1.0f / (1.0f + __expf(-x)); }
__device__ __forceinline__ float tanhfast(float x) { return 2.0f / (1.0f + __expf(-2.0f * x)) - 1.0f; }

// ---------------- pack W_ih (concat f,b) into bf16 [1024][320] ----------------
__global__ void pack_w_kernel(const float* __restrict__ Wf, const float* __restrict__ Wb,
                              unsigned short* __restrict__ Wp) {
    int g = blockIdx.x;          // 0..1023
    int k = threadIdx.x;         // 0..319
    float v = 0.0f;
    if (k < E_) v = (g < G4) ? Wf[g * E_ + k] : Wb[(g - G4) * E_ + k];
    Wp[g * KP + k] = f2bf(v);
}

// ---------------- gather + pack embedding rows into bf16 [49152][320] --------
__global__ void pack_emb_kernel(const float* __restrict__ emb, const int* __restrict__ sent,
                                unsigned short* __restrict__ A) {
    int m = blockIdx.x;          // 0..49151
    int k = threadIdx.x;         // 0..319
    int tok = sent[m];
    float v = 0.0f;
    if (k < E_) v = emb[(size_t)tok * E_ + k];
    A[(size_t)m * KP + k] = f2bf(v);
}

// ---------------- bf16 MFMA GEMM: gx = emb @ W^T + bias, permuted ------------
// N-tile bx covers dir d=bx>>2, unit-groups w in {w0,w0+1}, w0=(bx&3)*2.
// B-tile row rho = ws*64 + j*16 + col  <->  Wp row d*512 + (8j+w0+ws)*16+col.
// Wave wc: acc[i][n2] holds gate type j=n2 of unit group w=w0+wc -> ushort4
// store at gx[row][d*512 + (w0+wc)*64 + col*4 + j].
__global__ __launch_bounds__(256, 2) void gemm_kernel(const unsigned short* __restrict__ A,
                                                      const unsigned short* __restrict__ Bw,
                                                      const float* __restrict__ bF,
                                                      const float* __restrict__ bB,
                                                      unsigned short* __restrict__ C) {
    __shared__ __align__(16) unsigned short As[128 * 64];
    __shared__ __align__(16) unsigned short Bs[128 * 64];
    const int tid  = threadIdx.x;
    const int lane = tid & 63;
    const int wave = tid >> 6;
    const int wr = wave >> 1, wc = wave & 1;
    const int colL = lane & 15;
    const int mBase = blockIdx.y * 128;
    const int bx = blockIdx.x;
    const int d  = bx >> 2;
    const int w0 = (bx & 3) * 2;
    f32x4 acc[4][4] = {};
    for (int k0 = 0; k0 < KP; k0 += 64) {
        #pragma unroll
        for (int j = 0; j < 4; j++) {
            int c   = tid + 256 * j;       // 16B chunk id 0..1023
            int row = c >> 3;
            int col = (c & 7) * 8;
            *(uint4*)(As + row * 64 + col) = *(const uint4*)(A + (size_t)(mBase + row) * KP + k0 + col);
            int ws = row >> 6, jj = (row >> 4) & 3, cc = row & 15;
            int srcrow = d * 512 + (8 * jj + w0 + ws) * 16 + cc;
            *(uint4*)(Bs + row * 64 + col) = *(const uint4*)(Bw + (size_t)srcrow * KP + k0 + col);
        }
        __syncthreads();
        #pragma unroll
        for (int ks = 0; ks < 2; ks++) {
            bf16x8 af[4], bfr[4];
            #pragma unroll
            for (int i = 0; i < 4; i++) {
                int arow = wr * 64 + i * 16 + colL;
                af[i]  = *(const bf16x8*)(As + arow * 64 + ks * 32 + (lane >> 4) * 8);
                int brow = wc * 64 + i * 16 + colL;
                bfr[i] = *(const bf16x8*)(Bs + brow * 64 + ks * 32 + (lane >> 4) * 8);
            }
            #pragma unroll
            for (int i = 0; i < 4; i++)
                #pragma unroll
                for (int n2 = 0; n2 < 4; n2++)
                    acc[i][n2] = __builtin_amdgcn_mfma_f32_16x16x32_bf16(af[i], bfr[n2], acc[i][n2], 0, 0, 0);
        }
        __syncthreads();
    }
    const float* bias_d = d ? bB : bF;
    float bj[4];
    #pragma unroll
    for (int n2 = 0; n2 < 4; n2++) bj[n2] = bias_d[(8 * n2 + w0 + wc) * 16 + colL];
    #pragma unroll
    for (int i = 0; i < 4; i++)
        #pragma unroll
        for (int r = 0; r < 4; r++) {
            int row = mBase + wr * 64 + i * 16 + (lane >> 4) * 4 + r;
            u16x4 v;
            #pragma unroll
            for (int n2 = 0; n2 < 4; n2++) v[n2] = f2bf(acc[i][n2][r] + bj[n2]);
            *(u16x4*)(C + (size_t)row * NG + d * 512 + (w0 + wc) * 64 + colL * 4) = v;
        }
}

// ---------------- MFMA LSTM recurrence + feats projection --------------------
// grid 32: block = (16 batch rows, dir). 576 threads = 9 waves.
// Waves 0-7: gate type j = acc group, unit group w = wave. Bf = 4x4 frags
//            (64 VGPRs). acc seeded with gx (bias pre-folded by GEMM).
// Wave 8:    feats(s-1) = Wfc_dir . h(s-1) via MFMA on the shared A-frags.
__global__ __launch_bounds__(576, 1) void lstm_kernel(const unsigned short* __restrict__ gxP,
                                                      const float* __restrict__ Whf,
                                                      const float* __restrict__ Whb,
                                                      const int* __restrict__ seq_len,
                                                      const float* __restrict__ Wfc,
                                                      float* __restrict__ featsF,
                                                      float* __restrict__ featsB) {
    __shared__ __align__(16) unsigned short hL[16 * HSTR];
    __shared__ int Ls[16];
    __shared__ int maxLs;
    const int tid  = threadIdx.x;
    const int wave = tid >> 6;
    const int lane = tid & 63;
    const int col  = lane & 15;
    const int quad = lane >> 4;
    const int dir  = blockIdx.x & 1;
    const int b0   = (blockIdx.x >> 1) * 16;
    const float* Whh = dir ? Whb : Whf;
    float* fOut = dir ? featsB : featsF;

    if (tid < 16) Ls[tid] = min(max(seq_len[b0 + tid], 1), T_);
    __syncthreads();
    if (tid == 0) { int m = 0; for (int i = 0; i < 16; i++) m = max(m, Ls[i]); maxLs = m; }
    __syncthreads();
    const int maxL = maxLs;
    int Lm[4];
    #pragma unroll
    for (int r = 0; r < 4; r++) Lm[r] = Ls[quad * 4 + r];

    bf16x8 Bf[4][4];          // W_hh fragments (waves 0-7), resident all steps
    bf16x8 Wf8[4];            // W_fc fragments (wave 8)
    u16x4  gxv[4];            // prefetched gx for current step
    if (wave < 8) {
        #pragma unroll
        for (int j = 0; j < 4; j++) {
            int gate = (8 * j + wave) * 16 + col;
            #pragma unroll
            for (int kc = 0; kc < 4; kc++) {
                const float* src = Whh + (size_t)gate * H_ + kc * 32 + quad * 8;
                #pragma unroll
                for (int e = 0; e < 8; e++) Bf[j][kc][e] = (short)f2bf(src[e]);
            }
        }
        #pragma unroll
        for (int r = 0; r < 4; r++) {
            int pos = dir ? (Lm[r] - 1) : 0;   // Lm >= 1 always
            gxv[r] = *(const u16x4*)(gxP + ((size_t)((b0 + quad * 4 + r) * T_ + pos)) * NG
                                         + dir * 512 + wave * 64 + col * 4);
        }
    } else {
        #pragma unroll
        for (int kc = 0; kc < 4; kc++)
            #pragma unroll
            for (int e = 0; e < 8; e++) {
                float v = (col < NT_) ? Wfc[col * 256 + dir * H_ + kc * 32 + quad * 8 + e] : 0.0f;
                Wf8[kc][e] = (short)f2bf(v);
            }
    }

    float cst[4] = {0.f, 0.f, 0.f, 0.f};
    bf16x8 Af[4];
    #pragma unroll
    for (int kc = 0; kc < 4; kc++)
        #pragma unroll
        for (int e = 0; e < 8; e++) Af[kc][e] = 0;   // h(-1) = 0

    for (int s = 0; s <= maxL; s++) {
        if (wave < 8) {
            if (s < maxL) {
                u16x4 cur[4];
                #pragma unroll
                for (int r = 0; r < 4; r++) cur[r] = gxv[r];
                // prefetch gx for step s+1
                #pragma unroll
                for (int r = 0; r < 4; r++) {
                    if (s + 1 < Lm[r]) {
                        int pos = dir ? (Lm[r] - 2 - s) : (s + 1);
                        gxv[r] = *(const u16x4*)(gxP + ((size_t)((b0 + quad * 4 + r) * T_ + pos)) * NG
                                                     + dir * 512 + wave * 64 + col * 4);
                    }
                }
                f32x4 acc[4];
                #pragma unroll
                for (int j = 0; j < 4; j++)
                    #pragma unroll
                    for (int r = 0; r < 4; r++) acc[j][r] = bf2f(cur[r][j]);   // gx (+bias) seed
                #pragma unroll
                for (int kc = 0; kc < 4; kc++)
                    #pragma unroll
                    for (int j = 0; j < 4; j++)
                        acc[j] = __builtin_amdgcn_mfma_f32_16x16x32_bf16(Af[kc], Bf[j][kc], acc[j], 0, 0, 0);
                #pragma unroll
                for (int r = 0; r < 4; r++) {
                    if (s < Lm[r]) {
                        float cn = sigf(acc[1][r]) * cst[r] + sigf(acc[0][r]) * tanhfast(acc[2][r]);
                        cst[r] = cn;
                        float hn = sigf(acc[3][r]) * tanhfast(cn);
                        hL[(quad * 4 + r) * HSTR + wave * 16 + col] = f2bf(hn);
                    }
                }
            }
        } else {
            if (s >= 1) {
                f32x4 fc = (f32x4){0.f, 0.f, 0.f, 0.f};
                #pragma unroll
                for (int kc = 0; kc < 4; kc++)
                    fc = __builtin_amdgcn_mfma_f32_16x16x32_bf16(Af[kc], Wf8[kc], fc, 0, 0, 0);
                if (col < NT_) {
                    #pragma unroll
                    for (int r = 0; r < 4; r++) {
                        if (s - 1 < Lm[r]) {
                            int pos = dir ? (Lm[r] - s) : (s - 1);
                            fOut[((size_t)(b0 + quad * 4 + r) * T_ + pos) * NT_ + col] = fc[r];
                        }
                    }
                }
            }
        }
        __syncthreads();
        if (s < maxL) {
            #pragma unroll
            for (int kc = 0; kc < 4; kc++)
                Af[kc] = *(const bf16x8*)(hL + col * HSTR + kc * 32 + quad * 8);
        }
        __syncthreads();
    }
}

// ---------------- CRF forward + gold, per-batch nll --------------------------
__global__ __launch_bounds__(256) void crf_kernel(const float* __restrict__ fF,
                                                  const float* __restrict__ fB,
                                                  const float* __restrict__ bfc,
                                                  const float* __restrict__ trans,
                                                  const int* __restrict__ tags,
                                                  const int* __restrict__ seq_len,
                                                  float* __restrict__ nll) {
    __shared__ float Tl[NT_][16];
    __shared__ float al[2][16][16];
    __shared__ float red[16][16];
    __shared__ float gred[16][16];
    const int tid = threadIdx.x;
    const int sub = tid >> 4, j = tid & 15;
    const int b = blockIdx.x * 16 + sub;
    for (int idx = tid; idx < NT_ * NT_; idx += 256) Tl[idx / NT_][idx % NT_] = trans[idx];
    float bj = 0.0f;
    if (j < NT_) { al[0][sub][j] = (j == 0) ? 0.0f : NEGV; bj = bfc[j]; }
    const int Lb = min(max(seq_len[b], 1), T_);
    const float* fFb = fF + (size_t)b * T_ * NT_;
    const float* fBb = fB + (size_t)b * T_ * NT_;
    __syncthreads();
    int cu = 0;
    for (int t = 0; t < T_; t++) {
        if (j < NT_) {
            float feat = bj;
            if (t < Lb) feat += fFb[t * NT_ + j] + fBb[t * NT_ + j];
            float m = -3.0e38f;
            #pragma unroll
            for (int i = 0; i < NT_; i++) m = fmaxf(m, al[cu][sub][i] + Tl[j][i]);
            float ss = 0.0f;
            #pragma unroll
            for (int i = 0; i < NT_; i++) ss += __expf(al[cu][sub][i] + Tl[j][i] - m);
            al[cu ^ 1][sub][j] = m + __logf(ss) + feat;
        }
        __syncthreads();
        cu ^= 1;
    }
    if (j < NT_) red[sub][j] = al[cu][sub][j] + Tl[10][j];   // + trans[STOP][j]
    // gold partials
    float gp = 0.0f;
    if (j < NT_) {
        const int* tg = tags + (size_t)b * T_;
        for (int t = j; t < T_; t += NT_) {
            int tt = tg[t];
            int pv = (t == 0) ? 0 : tg[t - 1];
            float e = bfc[tt];
            if (t < Lb) e += fFb[t * NT_ + tt] + fBb[t * NT_ + tt];
            gp += Tl[tt][pv] + e;
        }
    }
    gred[sub][j] = gp;
    __syncthreads();
    if (j == 0) {
        float m = red[sub][0];
        #pragma unroll
        for (int i = 1; i < NT_; i++) m = fmaxf(m, red[sub][i]);
        float ss = 0.0f;
        #pragma unroll
        for (int i = 0; i < NT_; i++) ss += __expf(red[sub][i] - m);
        float fwd = m + __logf(ss);
        float gold = 0.0f;
        for (int i = 0; i < NT_; i++) gold += gred[sub][i];
        gold += Tl[10][tags[(size_t)b * T_ + (T_ - 1)]];
        nll[b] = fwd - gold;
    }
}

__global__ void reduce_mean_kernel(const float* __restrict__ nll, float* __restrict__ out) {
    int tid = threadIdx.x;
    float v = nll[tid];
    for (int o = 32; o > 0; o >>= 1) v += __shfl_down(v, o, 64);
    __shared__ float wsum[4];
    if ((tid & 63) == 0) wsum[tid >> 6] = v;
    __syncthreads();
    if (tid == 0) out[0] = (wsum[0] + wsum[1] + wsum[2] + wsum[3]) * (1.0f / 256.0f);
}

extern "C" void kernel_launch(void* const* d_in, const int* in_sizes, int n_in,
                              void* d_out, int out_size, void* d_ws, size_t ws_size,
                              hipStream_t stream) {
    const int*   sentence  = (const int*)d_in[0];
    const int*   seq_len   = (const int*)d_in[1];
    const int*   tags      = (const int*)d_in[2];
    const float* embedding = (const float*)d_in[3];
    const float* W_ih_f    = (const float*)d_in[4];
    const float* W_hh_f    = (const float*)d_in[5];
    const float* b_f       = (const float*)d_in[6];
    const float* W_ih_b    = (const float*)d_in[7];
    const float* W_hh_b    = (const float*)d_in[8];
    const float* b_b       = (const float*)d_in[9];
    const float* W_fc      = (const float*)d_in[10];
    const float* b_fc      = (const float*)d_in[11];
    const float* trans     = (const float*)d_in[12];
    float* out = (float*)d_out;

    char* ws = (char*)d_ws;
    const size_t M = (size_t)B_ * T_;                   // 49152
    unsigned short* Wp    = (unsigned short*)(ws);                       // 1024*320*2 = 655360
    unsigned short* Ap    = (unsigned short*)(ws + 655360);              // 49152*320*2 = 31457280
    unsigned short* gx    = (unsigned short*)(ws + 655360 + 31457280);   // 49152*1024*2 = 100663296
    float* featsF = (float*)(ws + 655360 + 31457280 + 100663296);        // 49152*13*4 = 2555904
    float* featsB = (float*)(ws + 655360 + 31457280 + 100663296 + 2555904);
    float* nll    = (float*)(ws + 655360 + 31457280 + 100663296 + 2 * 2555904);

    pack_w_kernel<<<NG, KP, 0, stream>>>(W_ih_f, W_ih_b, Wp);
    pack_emb_kernel<<<(int)M, KP, 0, stream>>>(embedding, sentence, Ap);
    dim3 gg(8, (int)(M / 128));
    gemm_kernel<<<gg, 256, 0, stream>>>(Ap, Wp, b_f, b_b, gx);
    lstm_kernel<<<32, 576, 0, stream>>>(gx, W_hh_f, W_hh_b, seq_len, W_fc, featsF, featsB);
    crf_kernel<<<B_ / 16, 256, 0, stream>>>(featsF, featsB, b_fc, trans, tags, seq_len, nll);
    reduce_mean_kernel<<<1, 256, 0, stream>>>(nll, out);
}

// Round 4
// 568.866 us; speedup vs baseline: 1.5104x; 1.2183x over previous
//
#include <hip/hip_runtime.h>
#include <hip/hip_bf16.h>

// BiLSTM-CRF fused pipeline for MI355X (gfx950).
// R4: LSTM recurrence restructured for latency:
//  - hL double-buffered -> ONE barrier per step (was 2)
//  - gx prefetch 2 steps deep (parity register slots; acc seeded before the
//    slot is overwritten) -> L3-hit latency hidden across ~2 full steps
//  - incremental gx addressing: per-row base ptr + frozen int offset
//  - loop unrolled x2 over parity so prefetch slots stay in registers
//  - wave 8 computes feats(s) right after the barrier (fresh Af), overlapped
//    with gate waves' step s+1; incremental feats store offsets.

#define B_   256
#define T_   192
#define E_   300
#define KP   320   // padded K
#define H_   128
#define G4   512   // 4*H
#define NG   1024  // both directions
#define NT_  13
#define NEGV -10000.0f
#define HSTR 144   // hL row stride in ushorts (288B, 16B-aligned)

typedef __attribute__((ext_vector_type(8))) short bf16x8;
typedef __attribute__((ext_vector_type(4))) float f32x4;
typedef __attribute__((ext_vector_type(4))) unsigned short u16x4;

__device__ __forceinline__ unsigned short f2bf(float f) {
    unsigned u = __float_as_uint(f);
    unsigned r = (u + 0x7FFFu + ((u >> 16) & 1u)) >> 16;   // RNE
    return (unsigned short)r;
}
__device__ __forceinline__ float bf2f(unsigned short h) {
    return __uint_as_float(((unsigned)h) << 16);
}
__device__ __forceinline__ float sigf(float x) { return 1.0f / (1.0f + __expf(-x)); }
__device__ __forceinline__ float tanhfast(float x) { return 2.0f / (1.0f + __expf(-2.0f * x)) - 1.0f; }

// ---------------- pack W_ih (concat f,b) into bf16 [1024][320] ----------------
__global__ void pack_w_kernel(const float* __restrict__ Wf, const float* __restrict__ Wb,
                              unsigned short* __restrict__ Wp) {
    int g = blockIdx.x;          // 0..1023
    int k = threadIdx.x;         // 0..319
    float v = 0.0f;
    if (k < E_) v = (g < G4) ? Wf[g * E_ + k] : Wb[(g - G4) * E_ + k];
    Wp[g * KP + k] = f2bf(v);
}

// ---------------- gather + pack embedding rows into bf16 [49152][320] --------
__global__ void pack_emb_kernel(const float* __restrict__ emb, const int* __restrict__ sent,
                                unsigned short* __restrict__ A) {
    int m = blockIdx.x;          // 0..49151
    int k = threadIdx.x;         // 0..319
    int tok = sent[m];
    float v = 0.0f;
    if (k < E_) v = emb[(size_t)tok * E_ + k];
    A[(size_t)m * KP + k] = f2bf(v);
}

// ---------------- bf16 MFMA GEMM: gx = emb @ W^T + bias, permuted ------------
__global__ __launch_bounds__(256, 2) void gemm_kernel(const unsigned short* __restrict__ A,
                                                      const unsigned short* __restrict__ Bw,
                                                      const float* __restrict__ bF,
                                                      const float* __restrict__ bB,
                                                      unsigned short* __restrict__ C) {
    __shared__ __align__(16) unsigned short As[128 * 64];
    __shared__ __align__(16) unsigned short Bs[128 * 64];
    const int tid  = threadIdx.x;
    const int lane = tid & 63;
    const int wave = tid >> 6;
    const int wr = wave >> 1, wc = wave & 1;
    const int colL = lane & 15;
    const int mBase = blockIdx.y * 128;
    const int bx = blockIdx.x;
    const int d  = bx >> 2;
    const int w0 = (bx & 3) * 2;
    f32x4 acc[4][4] = {};
    for (int k0 = 0; k0 < KP; k0 += 64) {
        #pragma unroll
        for (int j = 0; j < 4; j++) {
            int c   = tid + 256 * j;       // 16B chunk id 0..1023
            int row = c >> 3;
            int col = (c & 7) * 8;
            *(uint4*)(As + row * 64 + col) = *(const uint4*)(A + (size_t)(mBase + row) * KP + k0 + col);
            int ws = row >> 6, jj = (row >> 4) & 3, cc = row & 15;
            int srcrow = d * 512 + (8 * jj + w0 + ws) * 16 + cc;
            *(uint4*)(Bs + row * 64 + col) = *(const uint4*)(Bw + (size_t)srcrow * KP + k0 + col);
        }
        __syncthreads();
        #pragma unroll
        for (int ks = 0; ks < 2; ks++) {
            bf16x8 af[4], bfr[4];
            #pragma unroll
            for (int i = 0; i < 4; i++) {
                int arow = wr * 64 + i * 16 + colL;
                af[i]  = *(const bf16x8*)(As + arow * 64 + ks * 32 + (lane >> 4) * 8);
                int brow = wc * 64 + i * 16 + colL;
                bfr[i] = *(const bf16x8*)(Bs + brow * 64 + ks * 32 + (lane >> 4) * 8);
            }
            #pragma unroll
            for (int i = 0; i < 4; i++)
                #pragma unroll
                for (int n2 = 0; n2 < 4; n2++)
                    acc[i][n2] = __builtin_amdgcn_mfma_f32_16x16x32_bf16(af[i], bfr[n2], acc[i][n2], 0, 0, 0);
        }
        __syncthreads();
    }
    const float* bias_d = d ? bB : bF;
    float bj[4];
    #pragma unroll
    for (int n2 = 0; n2 < 4; n2++) bj[n2] = bias_d[(8 * n2 + w0 + wc) * 16 + colL];
    #pragma unroll
    for (int i = 0; i < 4; i++)
        #pragma unroll
        for (int r = 0; r < 4; r++) {
            int row = mBase + wr * 64 + i * 16 + (lane >> 4) * 4 + r;
            u16x4 v;
            #pragma unroll
            for (int n2 = 0; n2 < 4; n2++) v[n2] = f2bf(acc[i][n2][r] + bj[n2]);
            *(u16x4*)(C + (size_t)row * NG + d * 512 + (w0 + wc) * 64 + colL * 4) = v;
        }
}

// ---------------- MFMA LSTM recurrence + feats projection --------------------
// grid 32: block = (16 batch rows, dir). 576 threads = 9 waves.
__global__ __launch_bounds__(576, 1) void lstm_kernel(const unsigned short* __restrict__ gxP,
                                                      const float* __restrict__ Whf,
                                                      const float* __restrict__ Whb,
                                                      const int* __restrict__ seq_len,
                                                      const float* __restrict__ Wfc,
                                                      float* __restrict__ featsF,
                                                      float* __restrict__ featsB) {
    __shared__ __align__(16) unsigned short hL[2][16 * HSTR];
    __shared__ int Ls[16];
    __shared__ int maxLs;
    const int tid  = threadIdx.x;
    const int wave = tid >> 6;
    const int lane = tid & 63;
    const int col  = lane & 15;
    const int quad = lane >> 4;
    const int dir  = blockIdx.x & 1;
    const int b0   = (blockIdx.x >> 1) * 16;
    const float* Whh = dir ? Whb : Whf;
    float* fOut = dir ? featsB : featsF;

    if (tid < 16) Ls[tid] = min(max(seq_len[b0 + tid], 1), T_);
    __syncthreads();
    if (tid == 0) { int m = 0; for (int i = 0; i < 16; i++) m = max(m, Ls[i]); maxLs = m; }
    __syncthreads();
    const int maxL = maxLs;
    int Lm[4];
    #pragma unroll
    for (int r = 0; r < 4; r++) Lm[r] = Ls[quad * 4 + r];

    const int dNG = dir ? -NG : NG;

    bf16x8 Bf[4][4];                      // W_hh fragments (waves 0-7)
    bf16x8 Wf8[4];                        // W_fc fragments (wave 8)
    const unsigned short* rb[4];          // per-row gx base (step-0 position)
    int ofs2[4];                          // element offset of the step-(s+2) load
    u16x4 gx0[4], gx1[4];                 // parity prefetch slots
    float* fbase[4];                      // wave-8 feats store base
    int foff[4];

    if (wave < 8) {
        #pragma unroll
        for (int j = 0; j < 4; j++) {
            int gate = (8 * j + wave) * 16 + col;
            #pragma unroll
            for (int kc = 0; kc < 4; kc++) {
                const float* src = Whh + (size_t)gate * H_ + kc * 32 + quad * 8;
                #pragma unroll
                for (int e = 0; e < 8; e++) Bf[j][kc][e] = (short)f2bf(src[e]);
            }
        }
        #pragma unroll
        for (int r = 0; r < 4; r++) {
            int row = b0 + quad * 4 + r;
            int p0 = dir ? (Lm[r] - 1) : 0;
            rb[r] = gxP + ((size_t)(row * T_ + p0)) * NG + dir * 512 + wave * 64 + col * 4;
            gx0[r] = *(const u16x4*)(rb[r]);
            gx1[r] = *(const u16x4*)(rb[r] + ((Lm[r] > 1) ? dNG : 0));
            ofs2[r] = min(2, Lm[r] - 1) * dNG;
        }
    } else {
        #pragma unroll
        for (int kc = 0; kc < 4; kc++)
            #pragma unroll
            for (int e = 0; e < 8; e++) {
                float v = (col < NT_) ? Wfc[col * 256 + dir * H_ + kc * 32 + quad * 8 + e] : 0.0f;
                Wf8[kc][e] = (short)f2bf(v);
            }
        #pragma unroll
        for (int r = 0; r < 4; r++) {
            fbase[r] = fOut + (size_t)(b0 + quad * 4 + r) * T_ * NT_ + col;
            foff[r] = (dir ? (Lm[r] - 1) : 0) * NT_;
        }
    }
    const int fd = dir ? -NT_ : NT_;

    float cst[4] = {0.f, 0.f, 0.f, 0.f};
    bf16x8 Af[4];
    #pragma unroll
    for (int kc = 0; kc < 4; kc++)
        #pragma unroll
        for (int e = 0; e < 8; e++) Af[kc][e] = 0;   // h(-1) = 0

    auto step_body = [&](int s, u16x4 (&gxs)[4], int par) {
        if (wave < 8) {
            f32x4 acc[4];
            #pragma unroll
            for (int j = 0; j < 4; j++)
                #pragma unroll
                for (int r = 0; r < 4; r++) acc[j][r] = bf2f(gxs[r][j]);   // gx (+bias) seed
            // prefetch gx for step s+2 into the slot just consumed
            #pragma unroll
            for (int r = 0; r < 4; r++) {
                gxs[r] = *(const u16x4*)(rb[r] + ofs2[r]);
                ofs2[r] = (s + 3 < Lm[r]) ? ofs2[r] + dNG : ofs2[r];
            }
            #pragma unroll
            for (int kc = 0; kc < 4; kc++)
                #pragma unroll
                for (int j = 0; j < 4; j++)
                    acc[j] = __builtin_amdgcn_mfma_f32_16x16x32_bf16(Af[kc], Bf[j][kc], acc[j], 0, 0, 0);
            #pragma unroll
            for (int r = 0; r < 4; r++) {
                if (s < Lm[r]) {
                    float cn = sigf(acc[1][r]) * cst[r] + sigf(acc[0][r]) * tanhfast(acc[2][r]);
                    cst[r] = cn;
                    float hn = sigf(acc[3][r]) * tanhfast(cn);
                    hL[par][(quad * 4 + r) * HSTR + wave * 16 + col] = f2bf(hn);
                }
            }
        }
        __syncthreads();
        #pragma unroll
        for (int kc = 0; kc < 4; kc++)
            Af[kc] = *(const bf16x8*)(&hL[par][col * HSTR + kc * 32 + quad * 8]);
        if (wave == 8) {
            f32x4 fc = (f32x4){0.f, 0.f, 0.f, 0.f};
            #pragma unroll
            for (int kc = 0; kc < 4; kc++)
                fc = __builtin_amdgcn_mfma_f32_16x16x32_bf16(Af[kc], Wf8[kc], fc, 0, 0, 0);
            if (col < NT_) {
                #pragma unroll
                for (int r = 0; r < 4; r++) {
                    if (s < Lm[r]) fbase[r][foff[r]] = fc[r];
                }
            }
            #pragma unroll
            for (int r = 0; r < 4; r++) foff[r] += fd;
        }
    };

    for (int s = 0; s < maxL; s += 2) {
        step_body(s, gx0, 0);
        if (s + 1 < maxL) step_body(s + 1, gx1, 1);
    }
}

// ---------------- CRF forward + gold, per-batch nll --------------------------
__global__ __launch_bounds__(256) void crf_kernel(const float* __restrict__ fF,
                                                  const float* __restrict__ fB,
                                                  const float* __restrict__ bfc,
                                                  const float* __restrict__ trans,
                                                  const int* __restrict__ tags,
                                                  const int* __restrict__ seq_len,
                                                  float* __restrict__ nll) {
    __shared__ float Tl[NT_][16];
    __shared__ float al[2][16][16];
    __shared__ float red[16][16];
    __shared__ float gred[16][16];
    const int tid = threadIdx.x;
    const int sub = tid >> 4, j = tid & 15;
    const int b = blockIdx.x * 16 + sub;
    for (int idx = tid; idx < NT_ * NT_; idx += 256) Tl[idx / NT_][idx % NT_] = trans[idx];
    float bj = 0.0f;
    if (j < NT_) { al[0][sub][j] = (j == 0) ? 0.0f : NEGV; bj = bfc[j]; }
    const int Lb = min(max(seq_len[b], 1), T_);
    const float* fFb = fF + (size_t)b * T_ * NT_;
    const float* fBb = fB + (size_t)b * T_ * NT_;
    __syncthreads();
    int cu = 0;
    for (int t = 0; t < T_; t++) {
        if (j < NT_) {
            float feat = bj;
            if (t < Lb) feat += fFb[t * NT_ + j] + fBb[t * NT_ + j];
            float m = -3.0e38f;
            #pragma unroll
            for (int i = 0; i < NT_; i++) m = fmaxf(m, al[cu][sub][i] + Tl[j][i]);
            float ss = 0.0f;
            #pragma unroll
            for (int i = 0; i < NT_; i++) ss += __expf(al[cu][sub][i] + Tl[j][i] - m);
            al[cu ^ 1][sub][j] = m + __logf(ss) + feat;
        }
        __syncthreads();
        cu ^= 1;
    }
    if (j < NT_) red[sub][j] = al[cu][sub][j] + Tl[10][j];   // + trans[STOP][j]
    // gold partials
    float gp = 0.0f;
    if (j < NT_) {
        const int* tg = tags + (size_t)b * T_;
        for (int t = j; t < T_; t += NT_) {
            int tt = tg[t];
            int pv = (t == 0) ? 0 : tg[t - 1];
            float e = bfc[tt];
            if (t < Lb) e += fFb[t * NT_ + tt] + fBb[t * NT_ + tt];
            gp += Tl[tt][pv] + e;
        }
    }
    gred[sub][j] = gp;
    __syncthreads();
    if (j == 0) {
        float m = red[sub][0];
        #pragma unroll
        for (int i = 1; i < NT_; i++) m = fmaxf(m, red[sub][i]);
        float ss = 0.0f;
        #pragma unroll
        for (int i = 0; i < NT_; i++) ss += __expf(red[sub][i] - m);
        float fwd = m + __logf(ss);
        float gold = 0.0f;
        for (int i = 0; i < NT_; i++) gold += gred[sub][i];
        gold += Tl[10][tags[(size_t)b * T_ + (T_ - 1)]];
        nll[b] = fwd - gold;
    }
}

__global__ void reduce_mean_kernel(const float* __restrict__ nll, float* __restrict__ out) {
    int tid = threadIdx.x;
    float v = nll[tid];
    for (int o = 32; o > 0; o >>= 1) v += __shfl_down(v, o, 64);
    __shared__ float wsum[4];
    if ((tid & 63) == 0) wsum[tid >> 6] = v;
    __syncthreads();
    if (tid == 0) out[0] = (wsum[0] + wsum[1] + wsum[2] + wsum[3]) * (1.0f / 256.0f);
}

extern "C" void kernel_launch(void* const* d_in, const int* in_sizes, int n_in,
                              void* d_out, int out_size, void* d_ws, size_t ws_size,
                              hipStream_t stream) {
    const int*   sentence  = (const int*)d_in[0];
    const int*   seq_len   = (const int*)d_in[1];
    const int*   tags      = (const int*)d_in[2];
    const float* embedding = (const float*)d_in[3];
    const float* W_ih_f    = (const float*)d_in[4];
    const float* W_hh_f    = (const float*)d_in[5];
    const float* b_f       = (const float*)d_in[6];
    const float* W_ih_b    = (const float*)d_in[7];
    const float* W_hh_b    = (const float*)d_in[8];
    const float* b_b       = (const float*)d_in[9];
    const float* W_fc      = (const float*)d_in[10];
    const float* b_fc      = (const float*)d_in[11];
    const float* trans     = (const float*)d_in[12];
    float* out = (float*)d_out;

    char* ws = (char*)d_ws;
    const size_t M = (size_t)B_ * T_;                   // 49152
    unsigned short* Wp    = (unsigned short*)(ws);                       // 1024*320*2 = 655360
    unsigned short* Ap    = (unsigned short*)(ws + 655360);              // 49152*320*2 = 31457280
    unsigned short* gx    = (unsigned short*)(ws + 655360 + 31457280);   // 49152*1024*2 = 100663296
    float* featsF = (float*)(ws + 655360 + 31457280 + 100663296);        // 49152*13*4 = 2555904
    float* featsB = (float*)(ws + 655360 + 31457280 + 100663296 + 2555904);
    float* nll    = (float*)(ws + 655360 + 31457280 + 100663296 + 2 * 2555904);

    pack_w_kernel<<<NG, KP, 0, stream>>>(W_ih_f, W_ih_b, Wp);
    pack_emb_kernel<<<(int)M, KP, 0, stream>>>(embedding, sentence, Ap);
    dim3 gg(8, (int)(M / 128));
    gemm_kernel<<<gg, 256, 0, stream>>>(Ap, Wp, b_f, b_b, gx);
    lstm_kernel<<<32, 576, 0, stream>>>(gx, W_hh_f, W_hh_b, seq_len, W_fc, featsF, featsB);
    crf_kernel<<<B_ / 16, 256, 0, stream>>>(featsF, featsB, b_fc, trans, tags, seq_len, nll);
    reduce_mean_kernel<<<1, 256, 0, stream>>>(nll, out);
}

// Round 5
// 463.247 us; speedup vs baseline: 1.8548x; 1.2280x over previous
//
#include <hip/hip_runtime.h>
#include <hip/hip_bf16.h>

// BiLSTM-CRF fused pipeline for MI355X (gfx950).
// R5: LSTM cycle-sink fixes:
//  - sigmoid/tanh via __builtin_amdgcn_rcpf (no fast-math: 1/x was compiling
//    to the 7-instr IEEE div sequence -> ~400 extra cyc/SIMD/step)
//  - raw "s_waitcnt lgkmcnt(0); s_barrier" instead of __syncthreads(): keeps
//    gx prefetch loads in flight across the barrier (compiler forces
//    vmcnt(0) before S_BARRIER otherwise -> prefetch was being drained)
//  - per-row length guards removed from activations (dead rows free-run,
//    bounded, never stored; only feats stores stay guarded)
//  - f2bf truncation (1 op) everywhere (threshold is 2% of 1.9e5 -- huge)
//  - pack_w + pack_emb merged into one launch.

#define B_   256
#define T_   192
#define E_   300
#define KP   320   // padded K
#define H_   128
#define G4   512   // 4*H
#define NG   1024  // both directions
#define NT_  13
#define NEGV -10000.0f
#define HSTR 144   // hL row stride in ushorts (288B, 16B-aligned)

typedef __attribute__((ext_vector_type(8))) short bf16x8;
typedef __attribute__((ext_vector_type(4))) float f32x4;
typedef __attribute__((ext_vector_type(4))) unsigned short u16x4;

__device__ __forceinline__ unsigned short f2bf(float f) {
    return (unsigned short)(__float_as_uint(f) >> 16);   // truncation: ample threshold
}
__device__ __forceinline__ float bf2f(unsigned short h) {
    return __uint_as_float(((unsigned)h) << 16);
}
__device__ __forceinline__ float sigf(float x) {
    return __builtin_amdgcn_rcpf(1.0f + __expf(-x));
}
__device__ __forceinline__ float tanhfast(float x) {
    return __builtin_amdgcn_rcpf(1.0f + __expf(-2.0f * x)) * 2.0f - 1.0f;
}
__device__ __forceinline__ void barrier_lgkm() {
    // LDS-visibility barrier WITHOUT the forced vmcnt(0) drain of __syncthreads
    asm volatile("s_waitcnt lgkmcnt(0)\n\ts_barrier" ::: "memory");
}

// ---------------- pack W_ih + gather/pack emb rows (one launch) --------------
__global__ void pack_kernel(const float* __restrict__ Wf, const float* __restrict__ Wb,
                            const float* __restrict__ emb, const int* __restrict__ sent,
                            unsigned short* __restrict__ Wp, unsigned short* __restrict__ A) {
    int blk = blockIdx.x;
    int k = threadIdx.x;
    if (blk < NG) {
        float v = 0.0f;
        if (k < E_) v = (blk < G4) ? Wf[blk * E_ + k] : Wb[(blk - G4) * E_ + k];
        Wp[blk * KP + k] = f2bf(v);
    } else {
        int m = blk - NG;
        int tok = sent[m];
        float v = 0.0f;
        if (k < E_) v = emb[(size_t)tok * E_ + k];
        A[(size_t)m * KP + k] = f2bf(v);
    }
}

// ---------------- bf16 MFMA GEMM: gx = emb @ W^T + bias, permuted ------------
__global__ __launch_bounds__(256, 2) void gemm_kernel(const unsigned short* __restrict__ A,
                                                      const unsigned short* __restrict__ Bw,
                                                      const float* __restrict__ bF,
                                                      const float* __restrict__ bB,
                                                      unsigned short* __restrict__ C) {
    __shared__ __align__(16) unsigned short As[128 * 64];
    __shared__ __align__(16) unsigned short Bs[128 * 64];
    const int tid  = threadIdx.x;
    const int lane = tid & 63;
    const int wave = tid >> 6;
    const int wr = wave >> 1, wc = wave & 1;
    const int colL = lane & 15;
    const int mBase = blockIdx.y * 128;
    const int bx = blockIdx.x;
    const int d  = bx >> 2;
    const int w0 = (bx & 3) * 2;
    f32x4 acc[4][4] = {};
    for (int k0 = 0; k0 < KP; k0 += 64) {
        #pragma unroll
        for (int j = 0; j < 4; j++) {
            int c   = tid + 256 * j;       // 16B chunk id 0..1023
            int row = c >> 3;
            int col = (c & 7) * 8;
            *(uint4*)(As + row * 64 + col) = *(const uint4*)(A + (size_t)(mBase + row) * KP + k0 + col);
            int ws = row >> 6, jj = (row >> 4) & 3, cc = row & 15;
            int srcrow = d * 512 + (8 * jj + w0 + ws) * 16 + cc;
            *(uint4*)(Bs + row * 64 + col) = *(const uint4*)(Bw + (size_t)srcrow * KP + k0 + col);
        }
        __syncthreads();
        #pragma unroll
        for (int ks = 0; ks < 2; ks++) {
            bf16x8 af[4], bfr[4];
            #pragma unroll
            for (int i = 0; i < 4; i++) {
                int arow = wr * 64 + i * 16 + colL;
                af[i]  = *(const bf16x8*)(As + arow * 64 + ks * 32 + (lane >> 4) * 8);
                int brow = wc * 64 + i * 16 + colL;
                bfr[i] = *(const bf16x8*)(Bs + brow * 64 + ks * 32 + (lane >> 4) * 8);
            }
            #pragma unroll
            for (int i = 0; i < 4; i++)
                #pragma unroll
                for (int n2 = 0; n2 < 4; n2++)
                    acc[i][n2] = __builtin_amdgcn_mfma_f32_16x16x32_bf16(af[i], bfr[n2], acc[i][n2], 0, 0, 0);
        }
        __syncthreads();
    }
    const float* bias_d = d ? bB : bF;
    float bj[4];
    #pragma unroll
    for (int n2 = 0; n2 < 4; n2++) bj[n2] = bias_d[(8 * n2 + w0 + wc) * 16 + colL];
    #pragma unroll
    for (int i = 0; i < 4; i++)
        #pragma unroll
        for (int r = 0; r < 4; r++) {
            int row = mBase + wr * 64 + i * 16 + (lane >> 4) * 4 + r;
            u16x4 v;
            #pragma unroll
            for (int n2 = 0; n2 < 4; n2++) v[n2] = f2bf(acc[i][n2][r] + bj[n2]);
            *(u16x4*)(C + (size_t)row * NG + d * 512 + (w0 + wc) * 64 + colL * 4) = v;
        }
}

// ---------------- MFMA LSTM recurrence + feats projection --------------------
// grid 32: block = (16 batch rows, dir). 576 threads = 9 waves.
__global__ __launch_bounds__(576, 1) void lstm_kernel(const unsigned short* __restrict__ gxP,
                                                      const float* __restrict__ Whf,
                                                      const float* __restrict__ Whb,
                                                      const int* __restrict__ seq_len,
                                                      const float* __restrict__ Wfc,
                                                      float* __restrict__ featsF,
                                                      float* __restrict__ featsB) {
    __shared__ __align__(16) unsigned short hL[2][16 * HSTR];
    __shared__ int Ls[16];
    __shared__ int maxLs;
    const int tid  = threadIdx.x;
    const int wave = tid >> 6;
    const int lane = tid & 63;
    const int col  = lane & 15;
    const int quad = lane >> 4;
    const int dir  = blockIdx.x & 1;
    const int b0   = (blockIdx.x >> 1) * 16;
    const float* Whh = dir ? Whb : Whf;
    float* fOut = dir ? featsB : featsF;

    if (tid < 16) Ls[tid] = min(max(seq_len[b0 + tid], 1), T_);
    __syncthreads();
    if (tid == 0) { int m = 0; for (int i = 0; i < 16; i++) m = max(m, Ls[i]); maxLs = m; }
    __syncthreads();
    const int maxL = maxLs;
    int Lm[4];
    #pragma unroll
    for (int r = 0; r < 4; r++) Lm[r] = Ls[quad * 4 + r];

    const int dNG = dir ? -NG : NG;

    bf16x8 Bf[4][4];                      // W_hh fragments (waves 0-7)
    bf16x8 Wf8[4];                        // W_fc fragments (wave 8)
    const unsigned short* rb[4];          // per-row gx base (step-0 position)
    int ofs2[4];                          // element offset of the step-(s+2) load
    u16x4 gx0[4], gx1[4];                 // parity prefetch slots
    float* fbase[4];                      // wave-8 feats store base
    int foff[4];

    if (wave < 8) {
        #pragma unroll
        for (int j = 0; j < 4; j++) {
            int gate = (8 * j + wave) * 16 + col;
            #pragma unroll
            for (int kc = 0; kc < 4; kc++) {
                const float* src = Whh + (size_t)gate * H_ + kc * 32 + quad * 8;
                #pragma unroll
                for (int e = 0; e < 8; e++) Bf[j][kc][e] = (short)f2bf(src[e]);
            }
        }
        #pragma unroll
        for (int r = 0; r < 4; r++) {
            int row = b0 + quad * 4 + r;
            int p0 = dir ? (Lm[r] - 1) : 0;
            rb[r] = gxP + ((size_t)(row * T_ + p0)) * NG + dir * 512 + wave * 64 + col * 4;
            gx0[r] = *(const u16x4*)(rb[r]);
            gx1[r] = *(const u16x4*)(rb[r] + ((Lm[r] > 1) ? dNG : 0));
            ofs2[r] = min(2, Lm[r] - 1) * dNG;
        }
    } else {
        #pragma unroll
        for (int kc = 0; kc < 4; kc++)
            #pragma unroll
            for (int e = 0; e < 8; e++) {
                float v = (col < NT_) ? Wfc[col * 256 + dir * H_ + kc * 32 + quad * 8 + e] : 0.0f;
                Wf8[kc][e] = (short)f2bf(v);
            }
        #pragma unroll
        for (int r = 0; r < 4; r++) {
            fbase[r] = fOut + (size_t)(b0 + quad * 4 + r) * T_ * NT_ + col;
            foff[r] = (dir ? (Lm[r] - 1) : 0) * NT_;
        }
    }
    const int fd = dir ? -NT_ : NT_;

    float cst[4] = {0.f, 0.f, 0.f, 0.f};
    bf16x8 Af[4];
    #pragma unroll
    for (int kc = 0; kc < 4; kc++)
        #pragma unroll
        for (int e = 0; e < 8; e++) Af[kc][e] = 0;   // h(-1) = 0

    auto step_body = [&](int s, u16x4 (&gxs)[4], int par) {
        if (wave < 8) {
            f32x4 acc[4];
            #pragma unroll
            for (int j = 0; j < 4; j++)
                #pragma unroll
                for (int r = 0; r < 4; r++) acc[j][r] = bf2f(gxs[r][j]);   // gx (+bias) seed
            // prefetch gx for step s+2 into the slot just consumed
            #pragma unroll
            for (int r = 0; r < 4; r++) {
                gxs[r] = *(const u16x4*)(rb[r] + ofs2[r]);
                ofs2[r] = (s + 3 < Lm[r]) ? ofs2[r] + dNG : ofs2[r];
            }
            #pragma unroll
            for (int kc = 0; kc < 4; kc++)
                #pragma unroll
                for (int j = 0; j < 4; j++)
                    acc[j] = __builtin_amdgcn_mfma_f32_16x16x32_bf16(Af[kc], Bf[j][kc], acc[j], 0, 0, 0);
            // activations: unconditional (dead rows free-run, bounded, unused)
            #pragma unroll
            for (int r = 0; r < 4; r++) {
                float cn = sigf(acc[1][r]) * cst[r] + sigf(acc[0][r]) * tanhfast(acc[2][r]);
                cst[r] = cn;
                float hn = sigf(acc[3][r]) * tanhfast(cn);
                hL[par][(quad * 4 + r) * HSTR + wave * 16 + col] = f2bf(hn);
            }
        }
        barrier_lgkm();
        #pragma unroll
        for (int kc = 0; kc < 4; kc++)
            Af[kc] = *(const bf16x8*)(&hL[par][col * HSTR + kc * 32 + quad * 8]);
        if (wave == 8) {
            f32x4 fc = (f32x4){0.f, 0.f, 0.f, 0.f};
            #pragma unroll
            for (int kc = 0; kc < 4; kc++)
                fc = __builtin_amdgcn_mfma_f32_16x16x32_bf16(Af[kc], Wf8[kc], fc, 0, 0, 0);
            if (col < NT_) {
                #pragma unroll
                for (int r = 0; r < 4; r++) {
                    if (s < Lm[r]) fbase[r][foff[r]] = fc[r];
                }
            }
            #pragma unroll
            for (int r = 0; r < 4; r++) foff[r] += fd;
        }
    };

    for (int s = 0; s < maxL; s += 2) {
        step_body(s, gx0, 0);
        if (s + 1 < maxL) step_body(s + 1, gx1, 1);
    }
}

// ---------------- CRF forward + gold, per-batch nll --------------------------
__global__ __launch_bounds__(256) void crf_kernel(const float* __restrict__ fF,
                                                  const float* __restrict__ fB,
                                                  const float* __restrict__ bfc,
                                                  const float* __restrict__ trans,
                                                  const int* __restrict__ tags,
                                                  const int* __restrict__ seq_len,
                                                  float* __restrict__ nll) {
    __shared__ float Tl[NT_][16];
    __shared__ float al[2][16][16];
    __shared__ float red[16][16];
    __shared__ float gred[16][16];
    const int tid = threadIdx.x;
    const int sub = tid >> 4, j = tid & 15;
    const int b = blockIdx.x * 16 + sub;
    for (int idx = tid; idx < NT_ * NT_; idx += 256) Tl[idx / NT_][idx % NT_] = trans[idx];
    float bj = 0.0f;
    if (j < NT_) { al[0][sub][j] = (j == 0) ? 0.0f : NEGV; bj = bfc[j]; }
    const int Lb = min(max(seq_len[b], 1), T_);
    const float* fFb = fF + (size_t)b * T_ * NT_;
    const float* fBb = fB + (size_t)b * T_ * NT_;
    __syncthreads();
    int cu = 0;
    for (int t = 0; t < T_; t++) {
        if (j < NT_) {
            float feat = bj;
            if (t < Lb) feat += fFb[t * NT_ + j] + fBb[t * NT_ + j];
            float m = -3.0e38f;
            #pragma unroll
            for (int i = 0; i < NT_; i++) m = fmaxf(m, al[cu][sub][i] + Tl[j][i]);
            float ss = 0.0f;
            #pragma unroll
            for (int i = 0; i < NT_; i++) ss += __expf(al[cu][sub][i] + Tl[j][i] - m);
            al[cu ^ 1][sub][j] = m + __logf(ss) + feat;
        }
        __syncthreads();
        cu ^= 1;
    }
    if (j < NT_) red[sub][j] = al[cu][sub][j] + Tl[10][j];   // + trans[STOP][j]
    // gold partials
    float gp = 0.0f;
    if (j < NT_) {
        const int* tg = tags + (size_t)b * T_;
        for (int t = j; t < T_; t += NT_) {
            int tt = tg[t];
            int pv = (t == 0) ? 0 : tg[t - 1];
            float e = bfc[tt];
            if (t < Lb) e += fFb[t * NT_ + tt] + fBb[t * NT_ + tt];
            gp += Tl[tt][pv] + e;
        }
    }
    gred[sub][j] = gp;
    __syncthreads();
    if (j == 0) {
        float m = red[sub][0];
        #pragma unroll
        for (int i = 1; i < NT_; i++) m = fmaxf(m, red[sub][i]);
        float ss = 0.0f;
        #pragma unroll
        for (int i = 0; i < NT_; i++) ss += __expf(red[sub][i] - m);
        float fwd = m + __logf(ss);
        float gold = 0.0f;
        for (int i = 0; i < NT_; i++) gold += gred[sub][i];
        gold += Tl[10][tags[(size_t)b * T_ + (T_ - 1)]];
        nll[b] = fwd - gold;
    }
}

__global__ void reduce_mean_kernel(const float* __restrict__ nll, float* __restrict__ out) {
    int tid = threadIdx.x;
    float v = nll[tid];
    for (int o = 32; o > 0; o >>= 1) v += __shfl_down(v, o, 64);
    __shared__ float wsum[4];
    if ((tid & 63) == 0) wsum[tid >> 6] = v;
    __syncthreads();
    if (tid == 0) out[0] = (wsum[0] + wsum[1] + wsum[2] + wsum[3]) * (1.0f / 256.0f);
}

extern "C" void kernel_launch(void* const* d_in, const int* in_sizes, int n_in,
                              void* d_out, int out_size, void* d_ws, size_t ws_size,
                              hipStream_t stream) {
    const int*   sentence  = (const int*)d_in[0];
    const int*   seq_len   = (const int*)d_in[1];
    const int*   tags      = (const int*)d_in[2];
    const float* embedding = (const float*)d_in[3];
    const float* W_ih_f    = (const float*)d_in[4];
    const float* W_hh_f    = (const float*)d_in[5];
    const float* b_f       = (const float*)d_in[6];
    const float* W_ih_b    = (const float*)d_in[7];
    const float* W_hh_b    = (const float*)d_in[8];
    const float* b_b       = (const float*)d_in[9];
    const float* W_fc      = (const float*)d_in[10];
    const float* b_fc      = (const float*)d_in[11];
    const float* trans     = (const float*)d_in[12];
    float* out = (float*)d_out;

    char* ws = (char*)d_ws;
    const size_t M = (size_t)B_ * T_;                   // 49152
    unsigned short* Wp    = (unsigned short*)(ws);                       // 1024*320*2 = 655360
    unsigned short* Ap    = (unsigned short*)(ws + 655360);              // 49152*320*2 = 31457280
    unsigned short* gx    = (unsigned short*)(ws + 655360 + 31457280);   // 49152*1024*2 = 100663296
    float* featsF = (float*)(ws + 655360 + 31457280 + 100663296);        // 49152*13*4 = 2555904
    float* featsB = (float*)(ws + 655360 + 31457280 + 100663296 + 2555904);
    float* nll    = (float*)(ws + 655360 + 31457280 + 100663296 + 2 * 2555904);

    pack_kernel<<<NG + (int)M, KP, 0, stream>>>(W_ih_f, W_ih_b, embedding, sentence, Wp, Ap);
    dim3 gg(8, (int)(M / 128));
    gemm_kernel<<<gg, 256, 0, stream>>>(Ap, Wp, b_f, b_b, gx);
    lstm_kernel<<<32, 576, 0, stream>>>(gx, W_hh_f, W_hh_b, seq_len, W_fc, featsF, featsB);
    crf_kernel<<<B_ / 16, 256, 0, stream>>>(featsF, featsB, b_fc, trans, tags, seq_len, nll);
    reduce_mean_kernel<<<1, 256, 0, stream>>>(nll, out);
}

// Round 6
// 377.508 us; speedup vs baseline: 2.2761x; 1.2271x over previous
//
#include <hip/hip_runtime.h>
#include <hip/hip_bf16.h>

// BiLSTM-CRF fused pipeline for MI355X (gfx950).
// R6: LSTM spread over 4x more CUs: 4 batch rows/block (grid 128), real rows
// at MFMA rows {0,4,8,12} -> each quad owns one row at acc reg 0. Per lane
// per step: 1 activation set (was 4), 1 gx load, 1 ds_write. Garbage MFMA
// rows are row-contained and never stored. W_hh pre-packed to bf16 fragment
// order in pack_kernel (16B vector loads at LSTM startup).

#define B_   256
#define T_   192
#define E_   300
#define KP   320   // padded K
#define H_   128
#define G4   512   // 4*H
#define NG   1024  // both directions
#define NT_  13
#define NEGV -10000.0f
#define HSTR 144   // hL row stride in ushorts (288B, 16B-aligned)

typedef __attribute__((ext_vector_type(8))) short bf16x8;
typedef __attribute__((ext_vector_type(4))) float f32x4;
typedef __attribute__((ext_vector_type(4))) unsigned short u16x4;

__device__ __forceinline__ unsigned short f2bf(float f) {
    return (unsigned short)(__float_as_uint(f) >> 16);   // truncation: ample threshold
}
__device__ __forceinline__ float bf2f(unsigned short h) {
    return __uint_as_float(((unsigned)h) << 16);
}
__device__ __forceinline__ float sigf(float x) {
    return __builtin_amdgcn_rcpf(1.0f + __expf(-x));
}
__device__ __forceinline__ float tanhfast(float x) {
    return __builtin_amdgcn_rcpf(1.0f + __expf(-2.0f * x)) * 2.0f - 1.0f;
}
__device__ __forceinline__ void barrier_lgkm() {
    // LDS-visibility barrier WITHOUT the forced vmcnt(0) drain of __syncthreads
    asm volatile("s_waitcnt lgkmcnt(0)\n\ts_barrier" ::: "memory");
}

// ------- pack W_ih + W_hh (frag order) + gather/pack emb rows (one launch) ---
__global__ void pack_kernel(const float* __restrict__ Wf, const float* __restrict__ Wb,
                            const float* __restrict__ Whf, const float* __restrict__ Whb,
                            const float* __restrict__ emb, const int* __restrict__ sent,
                            unsigned short* __restrict__ Wp, unsigned short* __restrict__ Whp,
                            unsigned short* __restrict__ A) {
    int blk = blockIdx.x;
    int k = threadIdx.x;
    if (blk < NG) {
        float v = 0.0f;
        if (k < E_) v = (blk < G4) ? Wf[blk * E_ + k] : Wb[(blk - G4) * E_ + k];
        Wp[blk * KP + k] = f2bf(v);
    } else if (blk < NG + 1024) {
        // W_hh -> bf16 fragment order: Whp[(((d*8+w)*4+j)*4+kc)*64 + lane]*8 + e
        int t = blk - NG;
        int d = t >> 9, g = t & 511;
        if (k < H_) {
            const float* src = d ? Whb : Whf;
            float v = src[g * H_ + k];
            int w = (g >> 4) & 7, j = g >> 7, colq = g & 15;
            int kc = k >> 5, quad = (k >> 3) & 3, e = k & 7;
            Whp[((((size_t)(d * 8 + w) * 4 + j) * 4 + kc) * 64 + quad * 16 + colq) * 8 + e] = f2bf(v);
        }
    } else {
        int m = blk - NG - 1024;
        int tok = sent[m];
        float v = 0.0f;
        if (k < E_) v = emb[(size_t)tok * E_ + k];
        A[(size_t)m * KP + k] = f2bf(v);
    }
}

// ---------------- bf16 MFMA GEMM: gx = emb @ W^T + bias, permuted ------------
__global__ __launch_bounds__(256, 2) void gemm_kernel(const unsigned short* __restrict__ A,
                                                      const unsigned short* __restrict__ Bw,
                                                      const float* __restrict__ bF,
                                                      const float* __restrict__ bB,
                                                      unsigned short* __restrict__ C) {
    __shared__ __align__(16) unsigned short As[128 * 64];
    __shared__ __align__(16) unsigned short Bs[128 * 64];
    const int tid  = threadIdx.x;
    const int lane = tid & 63;
    const int wave = tid >> 6;
    const int wr = wave >> 1, wc = wave & 1;
    const int colL = lane & 15;
    const int mBase = blockIdx.y * 128;
    const int bx = blockIdx.x;
    const int d  = bx >> 2;
    const int w0 = (bx & 3) * 2;
    f32x4 acc[4][4] = {};
    for (int k0 = 0; k0 < KP; k0 += 64) {
        #pragma unroll
        for (int j = 0; j < 4; j++) {
            int c   = tid + 256 * j;       // 16B chunk id 0..1023
            int row = c >> 3;
            int col = (c & 7) * 8;
            *(uint4*)(As + row * 64 + col) = *(const uint4*)(A + (size_t)(mBase + row) * KP + k0 + col);
            int ws = row >> 6, jj = (row >> 4) & 3, cc = row & 15;
            int srcrow = d * 512 + (8 * jj + w0 + ws) * 16 + cc;
            *(uint4*)(Bs + row * 64 + col) = *(const uint4*)(Bw + (size_t)srcrow * KP + k0 + col);
        }
        __syncthreads();
        #pragma unroll
        for (int ks = 0; ks < 2; ks++) {
            bf16x8 af[4], bfr[4];
            #pragma unroll
            for (int i = 0; i < 4; i++) {
                int arow = wr * 64 + i * 16 + colL;
                af[i]  = *(const bf16x8*)(As + arow * 64 + ks * 32 + (lane >> 4) * 8);
                int brow = wc * 64 + i * 16 + colL;
                bfr[i] = *(const bf16x8*)(Bs + brow * 64 + ks * 32 + (lane >> 4) * 8);
            }
            #pragma unroll
            for (int i = 0; i < 4; i++)
                #pragma unroll
                for (int n2 = 0; n2 < 4; n2++)
                    acc[i][n2] = __builtin_amdgcn_mfma_f32_16x16x32_bf16(af[i], bfr[n2], acc[i][n2], 0, 0, 0);
        }
        __syncthreads();
    }
    const float* bias_d = d ? bB : bF;
    float bj[4];
    #pragma unroll
    for (int n2 = 0; n2 < 4; n2++) bj[n2] = bias_d[(8 * n2 + w0 + wc) * 16 + colL];
    #pragma unroll
    for (int i = 0; i < 4; i++)
        #pragma unroll
        for (int r = 0; r < 4; r++) {
            int row = mBase + wr * 64 + i * 16 + (lane >> 4) * 4 + r;
            u16x4 v;
            #pragma unroll
            for (int n2 = 0; n2 < 4; n2++) v[n2] = f2bf(acc[i][n2][r] + bj[n2]);
            *(u16x4*)(C + (size_t)row * NG + d * 512 + (w0 + wc) * 64 + colL * 4) = v;
        }
}

// ---------------- MFMA LSTM recurrence + feats projection --------------------
// grid 128: block = (4 batch rows, dir). 576 threads = 9 waves.
// Real rows at MFMA rows {0,4,8,12}: quad q owns block row q at acc reg 0.
__global__ __launch_bounds__(576, 1) void lstm_kernel(const unsigned short* __restrict__ gxP,
                                                      const unsigned short* __restrict__ Whp,
                                                      const int* __restrict__ seq_len,
                                                      const float* __restrict__ Wfc,
                                                      float* __restrict__ featsF,
                                                      float* __restrict__ featsB) {
    __shared__ __align__(16) unsigned short hL[2][16 * HSTR];
    __shared__ int Ls[4];
    __shared__ int maxLs;
    const int tid  = threadIdx.x;
    const int wave = tid >> 6;
    const int lane = tid & 63;
    const int col  = lane & 15;
    const int quad = lane >> 4;
    const int dir  = blockIdx.x & 1;
    const int b0   = (blockIdx.x >> 1) * 4;
    float* fOut = dir ? featsB : featsF;

    if (tid < 4) Ls[tid] = min(max(seq_len[b0 + tid], 1), T_);
    __syncthreads();
    if (tid == 0) { int m = 0; for (int i = 0; i < 4; i++) m = max(m, Ls[i]); maxLs = m; }
    __syncthreads();
    const int maxL = maxLs;
    const int Lq = Ls[quad];              // this lane's row length
    const int dNG = dir ? -NG : NG;

    bf16x8 Bf[4][4];                      // W_hh fragments (waves 0-7)
    bf16x8 Wf8[4];                        // W_fc fragments (wave 8)
    const unsigned short* rb = nullptr;   // this lane's gx base (step-0 pos)
    int ofs2 = 0;                         // element offset of the step-(s+2) load
    u16x4 gx0v = {}, gx1v = {};           // parity prefetch slots
    float* fb = nullptr;                  // wave-8 feats store base
    int foff = 0;

    if (wave < 8) {
        #pragma unroll
        for (int j = 0; j < 4; j++)
            #pragma unroll
            for (int kc = 0; kc < 4; kc++)
                Bf[j][kc] = *(const bf16x8*)(Whp +
                    ((((size_t)(dir * 8 + wave) * 4 + j) * 4 + kc) * 64 + lane) * 8);
        int row = b0 + quad;
        int p0 = dir ? (Lq - 1) : 0;
        rb = gxP + ((size_t)(row * T_ + p0)) * NG + dir * 512 + wave * 64 + col * 4;
        gx0v = *(const u16x4*)(rb);
        gx1v = *(const u16x4*)(rb + ((Lq > 1) ? dNG : 0));
        ofs2 = min(2, Lq - 1) * dNG;
    } else {
        #pragma unroll
        for (int kc = 0; kc < 4; kc++)
            #pragma unroll
            for (int e = 0; e < 8; e++) {
                float v = (col < NT_) ? Wfc[col * 256 + dir * H_ + kc * 32 + quad * 8 + e] : 0.0f;
                Wf8[kc][e] = (short)f2bf(v);
            }
        fb = fOut + (size_t)(b0 + quad) * T_ * NT_ + col;
        foff = (dir ? (Lq - 1) : 0) * NT_;
    }
    const int fd = dir ? -NT_ : NT_;

    float cst = 0.0f;
    bf16x8 Af[4];
    #pragma unroll
    for (int kc = 0; kc < 4; kc++)
        #pragma unroll
        for (int e = 0; e < 8; e++) Af[kc][e] = 0;   // h(-1) = 0

    auto step_body = [&](int s, u16x4& gxs, int par) {
        if (wave < 8) {
            f32x4 acc[4];
            #pragma unroll
            for (int j = 0; j < 4; j++) {
                acc[j][0] = bf2f(gxs[j]);            // gx (+bias) seed, real row
                acc[j][1] = 0.f; acc[j][2] = 0.f; acc[j][3] = 0.f;
            }
            // prefetch gx for step s+2 into the slot just consumed
            gxs = *(const u16x4*)(rb + ofs2);
            ofs2 = (s + 3 < Lq) ? ofs2 + dNG : ofs2;
            #pragma unroll
            for (int kc = 0; kc < 4; kc++)
                #pragma unroll
                for (int j = 0; j < 4; j++)
                    acc[j] = __builtin_amdgcn_mfma_f32_16x16x32_bf16(Af[kc], Bf[j][kc], acc[j], 0, 0, 0);
            float cn = sigf(acc[1][0]) * cst + sigf(acc[0][0]) * tanhfast(acc[2][0]);
            cst = cn;
            float hn = sigf(acc[3][0]) * tanhfast(cn);
            hL[par][(quad * 4) * HSTR + wave * 16 + col] = f2bf(hn);
        }
        barrier_lgkm();
        #pragma unroll
        for (int kc = 0; kc < 4; kc++)
            Af[kc] = *(const bf16x8*)(&hL[par][col * HSTR + kc * 32 + quad * 8]);
        if (wave == 8) {
            f32x4 fc = (f32x4){0.f, 0.f, 0.f, 0.f};
            #pragma unroll
            for (int kc = 0; kc < 4; kc++)
                fc = __builtin_amdgcn_mfma_f32_16x16x32_bf16(Af[kc], Wf8[kc], fc, 0, 0, 0);
            if (col < NT_ && s < Lq) fb[foff] = fc[0];
            foff += fd;
        }
    };

    for (int s = 0; s < maxL; s += 2) {
        step_body(s, gx0v, 0);
        if (s + 1 < maxL) step_body(s + 1, gx1v, 1);
    }
}

// ---------------- CRF forward + gold, per-batch nll --------------------------
__global__ __launch_bounds__(256) void crf_kernel(const float* __restrict__ fF,
                                                  const float* __restrict__ fB,
                                                  const float* __restrict__ bfc,
                                                  const float* __restrict__ trans,
                                                  const int* __restrict__ tags,
                                                  const int* __restrict__ seq_len,
                                                  float* __restrict__ nll) {
    __shared__ float Tl[NT_][16];
    __shared__ float al[2][16][16];
    __shared__ float red[16][16];
    __shared__ float gred[16][16];
    const int tid = threadIdx.x;
    const int sub = tid >> 4, j = tid & 15;
    const int b = blockIdx.x * 16 + sub;
    for (int idx = tid; idx < NT_ * NT_; idx += 256) Tl[idx / NT_][idx % NT_] = trans[idx];
    float bj = 0.0f;
    if (j < NT_) { al[0][sub][j] = (j == 0) ? 0.0f : NEGV; bj = bfc[j]; }
    const int Lb = min(max(seq_len[b], 1), T_);
    const float* fFb = fF + (size_t)b * T_ * NT_;
    const float* fBb = fB + (size_t)b * T_ * NT_;
    __syncthreads();
    int cu = 0;
    for (int t = 0; t < T_; t++) {
        if (j < NT_) {
            float feat = bj;
            if (t < Lb) feat += fFb[t * NT_ + j] + fBb[t * NT_ + j];
            float m = -3.0e38f;
            #pragma unroll
            for (int i = 0; i < NT_; i++) m = fmaxf(m, al[cu][sub][i] + Tl[j][i]);
            float ss = 0.0f;
            #pragma unroll
            for (int i = 0; i < NT_; i++) ss += __expf(al[cu][sub][i] + Tl[j][i] - m);
            al[cu ^ 1][sub][j] = m + __logf(ss) + feat;
        }
        __syncthreads();
        cu ^= 1;
    }
    if (j < NT_) red[sub][j] = al[cu][sub][j] + Tl[10][j];   // + trans[STOP][j]
    // gold partials
    float gp = 0.0f;
    if (j < NT_) {
        const int* tg = tags + (size_t)b * T_;
        for (int t = j; t < T_; t += NT_) {
            int tt = tg[t];
            int pv = (t == 0) ? 0 : tg[t - 1];
            float e = bfc[tt];
            if (t < Lb) e += fFb[t * NT_ + tt] + fBb[t * NT_ + tt];
            gp += Tl[tt][pv] + e;
        }
    }
    gred[sub][j] = gp;
    __syncthreads();
    if (j == 0) {
        float m = red[sub][0];
        #pragma unroll
        for (int i = 1; i < NT_; i++) m = fmaxf(m, red[sub][i]);
        float ss = 0.0f;
        #pragma unroll
        for (int i = 0; i < NT_; i++) ss += __expf(red[sub][i] - m);
        float fwd = m + __logf(ss);
        float gold = 0.0f;
        for (int i = 0; i < NT_; i++) gold += gred[sub][i];
        gold += Tl[10][tags[(size_t)b * T_ + (T_ - 1)]];
        nll[b] = fwd - gold;
    }
}

__global__ void reduce_mean_kernel(const float* __restrict__ nll, float* __restrict__ out) {
    int tid = threadIdx.x;
    float v = nll[tid];
    for (int o = 32; o > 0; o >>= 1) v += __shfl_down(v, o, 64);
    __shared__ float wsum[4];
    if ((tid & 63) == 0) wsum[tid >> 6] = v;
    __syncthreads();
    if (tid == 0) out[0] = (wsum[0] + wsum[1] + wsum[2] + wsum[3]) * (1.0f / 256.0f);
}

extern "C" void kernel_launch(void* const* d_in, const int* in_sizes, int n_in,
                              void* d_out, int out_size, void* d_ws, size_t ws_size,
                              hipStream_t stream) {
    const int*   sentence  = (const int*)d_in[0];
    const int*   seq_len   = (const int*)d_in[1];
    const int*   tags      = (const int*)d_in[2];
    const float* embedding = (const float*)d_in[3];
    const float* W_ih_f    = (const float*)d_in[4];
    const float* W_hh_f    = (const float*)d_in[5];
    const float* b_f       = (const float*)d_in[6];
    const float* W_ih_b    = (const float*)d_in[7];
    const float* W_hh_b    = (const float*)d_in[8];
    const float* b_b       = (const float*)d_in[9];
    const float* W_fc      = (const float*)d_in[10];
    const float* b_fc      = (const float*)d_in[11];
    const float* trans     = (const float*)d_in[12];
    float* out = (float*)d_out;

    char* ws = (char*)d_ws;
    const size_t M = (size_t)B_ * T_;                   // 49152
    unsigned short* Wp    = (unsigned short*)(ws);                       // 1024*320*2   = 655360
    unsigned short* Ap    = (unsigned short*)(ws + 655360);              // 49152*320*2  = 31457280
    unsigned short* gx    = (unsigned short*)(ws + 32112640);            // 49152*1024*2 = 100663296
    float* featsF = (float*)(ws + 132775936);                            // 49152*13*4   = 2555904
    float* featsB = (float*)(ws + 135331840);
    float* nll    = (float*)(ws + 137887744);                            // 1024
    unsigned short* Whp   = (unsigned short*)(ws + 137888768);           // 2*512*128*2  = 262144

    pack_kernel<<<NG + 1024 + (int)M, KP, 0, stream>>>(W_ih_f, W_ih_b, W_hh_f, W_hh_b,
                                                       embedding, sentence, Wp, Whp, Ap);
    dim3 gg(8, (int)(M / 128));
    gemm_kernel<<<gg, 256, 0, stream>>>(Ap, Wp, b_f, b_b, gx);
    lstm_kernel<<<128, 576, 0, stream>>>(gx, Whp, seq_len, W_fc, featsF, featsB);
    crf_kernel<<<B_ / 16, 256, 0, stream>>>(featsF, featsB, b_fc, trans, tags, seq_len, nll);
    reduce_mean_kernel<<<1, 256, 0, stream>>>(nll, out);
}

// Round 7
// 330.205 us; speedup vs baseline: 2.6021x; 1.1433x over previous
//
#include <hip/hip_runtime.h>
#include <hip/hip_bf16.h>

// BiLSTM-CRF fused pipeline for MI355X (gfx950).
// R7: CRF rewritten as one wave per batch row (grid 256, 16x CU spread).
// trans row + bias in registers; alpha via same-address LDS broadcasts
// (conflict-free, single-wave -> no barriers); feats staged via float4 bulk
// loads one 16-step chunk ahead; max/sum as explicit trees; gold + final
// LSE by wave shuffles in the same kernel.

#define B_   256
#define T_   192
#define E_   300
#define KP   320   // padded K
#define H_   128
#define G4   512   // 4*H
#define NG   1024  // both directions
#define NT_  13
#define NEGV -10000.0f
#define HSTR 144   // hL row stride in ushorts (288B, 16B-aligned)

typedef __attribute__((ext_vector_type(8))) short bf16x8;
typedef __attribute__((ext_vector_type(4))) float f32x4;
typedef __attribute__((ext_vector_type(4))) unsigned short u16x4;

__device__ __forceinline__ unsigned short f2bf(float f) {
    return (unsigned short)(__float_as_uint(f) >> 16);   // truncation: ample threshold
}
__device__ __forceinline__ float bf2f(unsigned short h) {
    return __uint_as_float(((unsigned)h) << 16);
}
__device__ __forceinline__ float sigf(float x) {
    return __builtin_amdgcn_rcpf(1.0f + __expf(-x));
}
__device__ __forceinline__ float tanhfast(float x) {
    return __builtin_amdgcn_rcpf(1.0f + __expf(-2.0f * x)) * 2.0f - 1.0f;
}
__device__ __forceinline__ void barrier_lgkm() {
    // LDS-visibility barrier WITHOUT the forced vmcnt(0) drain of __syncthreads
    asm volatile("s_waitcnt lgkmcnt(0)\n\ts_barrier" ::: "memory");
}

// ------- pack W_ih + W_hh (frag order) + gather/pack emb rows (one launch) ---
__global__ void pack_kernel(const float* __restrict__ Wf, const float* __restrict__ Wb,
                            const float* __restrict__ Whf, const float* __restrict__ Whb,
                            const float* __restrict__ emb, const int* __restrict__ sent,
                            unsigned short* __restrict__ Wp, unsigned short* __restrict__ Whp,
                            unsigned short* __restrict__ A) {
    int blk = blockIdx.x;
    int k = threadIdx.x;
    if (blk < NG) {
        float v = 0.0f;
        if (k < E_) v = (blk < G4) ? Wf[blk * E_ + k] : Wb[(blk - G4) * E_ + k];
        Wp[blk * KP + k] = f2bf(v);
    } else if (blk < NG + 1024) {
        // W_hh -> bf16 fragment order: Whp[(((d*8+w)*4+j)*4+kc)*64 + lane]*8 + e
        int t = blk - NG;
        int d = t >> 9, g = t & 511;
        if (k < H_) {
            const float* src = d ? Whb : Whf;
            float v = src[g * H_ + k];
            int w = (g >> 4) & 7, j = g >> 7, colq = g & 15;
            int kc = k >> 5, quad = (k >> 3) & 3, e = k & 7;
            Whp[((((size_t)(d * 8 + w) * 4 + j) * 4 + kc) * 64 + quad * 16 + colq) * 8 + e] = f2bf(v);
        }
    } else {
        int m = blk - NG - 1024;
        int tok = sent[m];
        float v = 0.0f;
        if (k < E_) v = emb[(size_t)tok * E_ + k];
        A[(size_t)m * KP + k] = f2bf(v);
    }
}

// ---------------- bf16 MFMA GEMM: gx = emb @ W^T + bias, permuted ------------
__global__ __launch_bounds__(256, 2) void gemm_kernel(const unsigned short* __restrict__ A,
                                                      const unsigned short* __restrict__ Bw,
                                                      const float* __restrict__ bF,
                                                      const float* __restrict__ bB,
                                                      unsigned short* __restrict__ C) {
    __shared__ __align__(16) unsigned short As[128 * 64];
    __shared__ __align__(16) unsigned short Bs[128 * 64];
    const int tid  = threadIdx.x;
    const int lane = tid & 63;
    const int wave = tid >> 6;
    const int wr = wave >> 1, wc = wave & 1;
    const int colL = lane & 15;
    const int mBase = blockIdx.y * 128;
    const int bx = blockIdx.x;
    const int d  = bx >> 2;
    const int w0 = (bx & 3) * 2;
    f32x4 acc[4][4] = {};
    for (int k0 = 0; k0 < KP; k0 += 64) {
        #pragma unroll
        for (int j = 0; j < 4; j++) {
            int c   = tid + 256 * j;       // 16B chunk id 0..1023
            int row = c >> 3;
            int col = (c & 7) * 8;
            *(uint4*)(As + row * 64 + col) = *(const uint4*)(A + (size_t)(mBase + row) * KP + k0 + col);
            int ws = row >> 6, jj = (row >> 4) & 3, cc = row & 15;
            int srcrow = d * 512 + (8 * jj + w0 + ws) * 16 + cc;
            *(uint4*)(Bs + row * 64 + col) = *(const uint4*)(Bw + (size_t)srcrow * KP + k0 + col);
        }
        __syncthreads();
        #pragma unroll
        for (int ks = 0; ks < 2; ks++) {
            bf16x8 af[4], bfr[4];
            #pragma unroll
            for (int i = 0; i < 4; i++) {
                int arow = wr * 64 + i * 16 + colL;
                af[i]  = *(const bf16x8*)(As + arow * 64 + ks * 32 + (lane >> 4) * 8);
                int brow = wc * 64 + i * 16 + colL;
                bfr[i] = *(const bf16x8*)(Bs + brow * 64 + ks * 32 + (lane >> 4) * 8);
            }
            #pragma unroll
            for (int i = 0; i < 4; i++)
                #pragma unroll
                for (int n2 = 0; n2 < 4; n2++)
                    acc[i][n2] = __builtin_amdgcn_mfma_f32_16x16x32_bf16(af[i], bfr[n2], acc[i][n2], 0, 0, 0);
        }
        __syncthreads();
    }
    const float* bias_d = d ? bB : bF;
    float bj[4];
    #pragma unroll
    for (int n2 = 0; n2 < 4; n2++) bj[n2] = bias_d[(8 * n2 + w0 + wc) * 16 + colL];
    #pragma unroll
    for (int i = 0; i < 4; i++)
        #pragma unroll
        for (int r = 0; r < 4; r++) {
            int row = mBase + wr * 64 + i * 16 + (lane >> 4) * 4 + r;
            u16x4 v;
            #pragma unroll
            for (int n2 = 0; n2 < 4; n2++) v[n2] = f2bf(acc[i][n2][r] + bj[n2]);
            *(u16x4*)(C + (size_t)row * NG + d * 512 + (w0 + wc) * 64 + colL * 4) = v;
        }
}

// ---------------- MFMA LSTM recurrence + feats projection --------------------
// grid 128: block = (4 batch rows, dir). 576 threads = 9 waves.
__global__ __launch_bounds__(576, 1) void lstm_kernel(const unsigned short* __restrict__ gxP,
                                                      const unsigned short* __restrict__ Whp,
                                                      const int* __restrict__ seq_len,
                                                      const float* __restrict__ Wfc,
                                                      float* __restrict__ featsF,
                                                      float* __restrict__ featsB) {
    __shared__ __align__(16) unsigned short hL[2][16 * HSTR];
    __shared__ int Ls[4];
    __shared__ int maxLs;
    const int tid  = threadIdx.x;
    const int wave = tid >> 6;
    const int lane = tid & 63;
    const int col  = lane & 15;
    const int quad = lane >> 4;
    const int dir  = blockIdx.x & 1;
    const int b0   = (blockIdx.x >> 1) * 4;
    float* fOut = dir ? featsB : featsF;

    if (tid < 4) Ls[tid] = min(max(seq_len[b0 + tid], 1), T_);
    __syncthreads();
    if (tid == 0) { int m = 0; for (int i = 0; i < 4; i++) m = max(m, Ls[i]); maxLs = m; }
    __syncthreads();
    const int maxL = maxLs;
    const int Lq = Ls[quad];              // this lane's row length
    const int dNG = dir ? -NG : NG;

    bf16x8 Bf[4][4];                      // W_hh fragments (waves 0-7)
    bf16x8 Wf8[4];                        // W_fc fragments (wave 8)
    const unsigned short* rb = nullptr;   // this lane's gx base (step-0 pos)
    int ofs2 = 0;                         // element offset of the step-(s+2) load
    u16x4 gx0v = {}, gx1v = {};           // parity prefetch slots
    float* fb = nullptr;                  // wave-8 feats store base
    int foff = 0;

    if (wave < 8) {
        #pragma unroll
        for (int j = 0; j < 4; j++)
            #pragma unroll
            for (int kc = 0; kc < 4; kc++)
                Bf[j][kc] = *(const bf16x8*)(Whp +
                    ((((size_t)(dir * 8 + wave) * 4 + j) * 4 + kc) * 64 + lane) * 8);
        int row = b0 + quad;
        int p0 = dir ? (Lq - 1) : 0;
        rb = gxP + ((size_t)(row * T_ + p0)) * NG + dir * 512 + wave * 64 + col * 4;
        gx0v = *(const u16x4*)(rb);
        gx1v = *(const u16x4*)(rb + ((Lq > 1) ? dNG : 0));
        ofs2 = min(2, Lq - 1) * dNG;
    } else {
        #pragma unroll
        for (int kc = 0; kc < 4; kc++)
            #pragma unroll
            for (int e = 0; e < 8; e++) {
                float v = (col < NT_) ? Wfc[col * 256 + dir * H_ + kc * 32 + quad * 8 + e] : 0.0f;
                Wf8[kc][e] = (short)f2bf(v);
            }
        fb = fOut + (size_t)(b0 + quad) * T_ * NT_ + col;
        foff = (dir ? (Lq - 1) : 0) * NT_;
    }
    const int fd = dir ? -NT_ : NT_;

    float cst = 0.0f;
    bf16x8 Af[4];
    #pragma unroll
    for (int kc = 0; kc < 4; kc++)
        #pragma unroll
        for (int e = 0; e < 8; e++) Af[kc][e] = 0;   // h(-1) = 0

    auto step_body = [&](int s, u16x4& gxs, int par) {
        if (wave < 8) {
            f32x4 acc[4];
            #pragma unroll
            for (int j = 0; j < 4; j++) {
                acc[j][0] = bf2f(gxs[j]);            // gx (+bias) seed, real row
                acc[j][1] = 0.f; acc[j][2] = 0.f; acc[j][3] = 0.f;
            }
            // prefetch gx for step s+2 into the slot just consumed
            gxs = *(const u16x4*)(rb + ofs2);
            ofs2 = (s + 3 < Lq) ? ofs2 + dNG : ofs2;
            #pragma unroll
            for (int kc = 0; kc < 4; kc++)
                #pragma unroll
                for (int j = 0; j < 4; j++)
                    acc[j] = __builtin_amdgcn_mfma_f32_16x16x32_bf16(Af[kc], Bf[j][kc], acc[j], 0, 0, 0);
            float cn = sigf(acc[1][0]) * cst + sigf(acc[0][0]) * tanhfast(acc[2][0]);
            cst = cn;
            float hn = sigf(acc[3][0]) * tanhfast(cn);
            hL[par][(quad * 4) * HSTR + wave * 16 + col] = f2bf(hn);
        }
        barrier_lgkm();
        #pragma unroll
        for (int kc = 0; kc < 4; kc++)
            Af[kc] = *(const bf16x8*)(&hL[par][col * HSTR + kc * 32 + quad * 8]);
        if (wave == 8) {
            f32x4 fc = (f32x4){0.f, 0.f, 0.f, 0.f};
            #pragma unroll
            for (int kc = 0; kc < 4; kc++)
                fc = __builtin_amdgcn_mfma_f32_16x16x32_bf16(Af[kc], Wf8[kc], fc, 0, 0, 0);
            if (col < NT_ && s < Lq) fb[foff] = fc[0];
            foff += fd;
        }
    };

    for (int s = 0; s < maxL; s += 2) {
        step_body(s, gx0v, 0);
        if (s + 1 < maxL) step_body(s + 1, gx1v, 1);
    }
}

// ---------------- CRF: one wave per batch row --------------------------------
// Lane j (0..12) owns tag j: trans[j][*] + bfc[j] in registers. Alpha in a
// 16-float LDS array read via same-address broadcasts. Feats staged one
// 16-step chunk ahead via float4 bulk loads (lanes 0..51).
__global__ __launch_bounds__(64) void crf_kernel(const float* __restrict__ fF,
                                                 const float* __restrict__ fB,
                                                 const float* __restrict__ bfc,
                                                 const float* __restrict__ trans,
                                                 const int* __restrict__ tags,
                                                 const int* __restrict__ seq_len,
                                                 float* __restrict__ nll) {
    __shared__ __align__(16) float al[16];
    __shared__ __align__(16) float feat_lds[2 * 208];
    __shared__ float Tlds[NT_ * NT_];
    const int lane = threadIdx.x;
    const int b = blockIdx.x;
    const int Lb = min(max(seq_len[b], 1), T_);
    const float* fFb = fF + (size_t)b * T_ * NT_;
    const float* fBb = fB + (size_t)b * T_ * NT_;
    const int* tg = tags + (size_t)b * T_;

    for (int i = lane; i < NT_ * NT_; i += 64) Tlds[i] = trans[i];

    const int jc = min(lane, NT_ - 1);
    float Tj[NT_];
    #pragma unroll
    for (int i = 0; i < NT_; i++) Tj[i] = trans[jc * NT_ + i];
    const float bj  = bfc[jc];
    const float T10 = trans[10 * NT_ + jc];
    if (lane < NT_) al[lane] = (lane == 0) ? 0.0f : NEGV;

    // stage chunk 0
    const int e0 = lane * 4;
    const bool ldact = (lane < 52);
    float4 vF = {}, vB = {};
    if (ldact) { vF = *(const float4*)(fFb + e0); vB = *(const float4*)(fBb + e0); }

    #pragma unroll 1
    for (int c = 0; c < 12; ++c) {
        if (ldact) {
            float4 w;
            #pragma unroll
            for (int k = 0; k < 4; k++) {
                unsigned g = (unsigned)(c * 208 + e0 + k);
                unsigned t = g / 13u;
                float s = ((const float*)&vF)[k] + ((const float*)&vB)[k];
                ((float*)&w)[k] = (t < (unsigned)Lb) ? s : 0.0f;
            }
            *(float4*)&feat_lds[(c & 1) * 208 + e0] = w;
            if (c < 11) {
                vF = *(const float4*)(fFb + (c + 1) * 208 + e0);
                vB = *(const float4*)(fBb + (c + 1) * 208 + e0);
            }
        }
        barrier_lgkm();
        const int fbase = (c & 1) * 208;
        for (int tt = 0; tt < 16; ++tt) {
            float4 A0 = *(const float4*)&al[0];
            float4 A1 = *(const float4*)&al[4];
            float4 A2 = *(const float4*)&al[8];
            float a12 = al[12];
            float feat = feat_lds[fbase + tt * NT_ + jc];
            float v0 = A0.x + Tj[0],  v1 = A0.y + Tj[1],  v2 = A0.z + Tj[2],  v3 = A0.w + Tj[3];
            float v4 = A1.x + Tj[4],  v5 = A1.y + Tj[5],  v6 = A1.z + Tj[6],  v7 = A1.w + Tj[7];
            float v8 = A2.x + Tj[8],  v9 = A2.y + Tj[9],  v10 = A2.z + Tj[10], v11 = A2.w + Tj[11];
            float v12 = a12 + Tj[12];
            float p0 = fmaxf(v0, v1), p1 = fmaxf(v2, v3), p2 = fmaxf(v4, v5);
            float p3 = fmaxf(v6, v7), p4 = fmaxf(v8, v9), p5 = fmaxf(v10, v11);
            float q0 = fmaxf(p0, p1), q1 = fmaxf(p2, p3), q2 = fmaxf(p4, p5);
            float m = fmaxf(fmaxf(q0, q1), fmaxf(q2, v12));
            float e0_ = __expf(v0 - m),  e1_ = __expf(v1 - m),  e2_ = __expf(v2 - m);
            float e3_ = __expf(v3 - m),  e4_ = __expf(v4 - m),  e5_ = __expf(v5 - m);
            float e6_ = __expf(v6 - m),  e7_ = __expf(v7 - m),  e8_ = __expf(v8 - m);
            float e9_ = __expf(v9 - m),  e10_ = __expf(v10 - m), e11_ = __expf(v11 - m);
            float e12_ = __expf(v12 - m);
            float s0 = e0_ + e1_, s1 = e2_ + e3_, s2 = e4_ + e5_, s3 = e6_ + e7_;
            float s4 = e8_ + e9_, s5 = e10_ + e11_;
            float u0 = s0 + s1, u1 = s2 + s3, u2 = s4 + s5;
            float ss = (u0 + u1) + (u2 + e12_);
            float alnew = m + __logf(ss) + feat + bj;
            barrier_lgkm();
            if (lane < NT_) al[lane] = alnew;
            barrier_lgkm();
        }
    }

    // gold score: t = lane, lane+64, lane+128
    float gp = 0.0f;
    #pragma unroll
    for (int u = 0; u < 3; ++u) {
        int t = lane + u * 64;
        int tt_ = tg[t];
        int pv = (t == 0) ? 0 : tg[t - 1];
        float e = bfc[tt_];
        if (t < Lb) e += fFb[t * NT_ + tt_] + fBb[t * NT_ + tt_];
        gp += Tlds[tt_ * NT_ + pv] + e;
    }
    #pragma unroll
    for (int o = 32; o > 0; o >>= 1) gp += __shfl_down(gp, o, 64);

    // fwd = LSE_j(alphaT[j] + trans[10][j])
    float vj = (lane < NT_) ? (al[lane] + T10) : -3.0e38f;
    float mm = vj;
    #pragma unroll
    for (int o = 32; o > 0; o >>= 1) mm = fmaxf(mm, __shfl_down(mm, o, 64));
    mm = __shfl(mm, 0, 64);
    float se = (lane < NT_) ? __expf(vj - mm) : 0.0f;
    #pragma unroll
    for (int o = 32; o > 0; o >>= 1) se += __shfl_down(se, o, 64);
    if (lane == 0) {
        float fwd = mm + __logf(se);
        float gold = gp + Tlds[10 * NT_ + tg[T_ - 1]];
        nll[b] = fwd - gold;
    }
}

__global__ void reduce_mean_kernel(const float* __restrict__ nll, float* __restrict__ out) {
    int tid = threadIdx.x;
    float v = nll[tid];
    for (int o = 32; o > 0; o >>= 1) v += __shfl_down(v, o, 64);
    __shared__ float wsum[4];
    if ((tid & 63) == 0) wsum[tid >> 6] = v;
    __syncthreads();
    if (tid == 0) out[0] = (wsum[0] + wsum[1] + wsum[2] + wsum[3]) * (1.0f / 256.0f);
}

extern "C" void kernel_launch(void* const* d_in, const int* in_sizes, int n_in,
                              void* d_out, int out_size, void* d_ws, size_t ws_size,
                              hipStream_t stream) {
    const int*   sentence  = (const int*)d_in[0];
    const int*   seq_len   = (const int*)d_in[1];
    const int*   tags      = (const int*)d_in[2];
    const float* embedding = (const float*)d_in[3];
    const float* W_ih_f    = (const float*)d_in[4];
    const float* W_hh_f    = (const float*)d_in[5];
    const float* b_f       = (const float*)d_in[6];
    const float* W_ih_b    = (const float*)d_in[7];
    const float* W_hh_b    = (const float*)d_in[8];
    const float* b_b       = (const float*)d_in[9];
    const float* W_fc      = (const float*)d_in[10];
    const float* b_fc      = (const float*)d_in[11];
    const float* trans     = (const float*)d_in[12];
    float* out = (float*)d_out;

    char* ws = (char*)d_ws;
    const size_t M = (size_t)B_ * T_;                   // 49152
    unsigned short* Wp    = (unsigned short*)(ws);                       // 1024*320*2   = 655360
    unsigned short* Ap    = (unsigned short*)(ws + 655360);              // 49152*320*2  = 31457280
    unsigned short* gx    = (unsigned short*)(ws + 32112640);            // 49152*1024*2 = 100663296
    float* featsF = (float*)(ws + 132775936);                            // 49152*13*4   = 2555904
    float* featsB = (float*)(ws + 135331840);
    float* nll    = (float*)(ws + 137887744);                            // 1024
    unsigned short* Whp   = (unsigned short*)(ws + 137888768);           // 2*512*128*2  = 262144

    pack_kernel<<<NG + 1024 + (int)M, KP, 0, stream>>>(W_ih_f, W_ih_b, W_hh_f, W_hh_b,
                                                       embedding, sentence, Wp, Whp, Ap);
    dim3 gg(8, (int)(M / 128));
    gemm_kernel<<<gg, 256, 0, stream>>>(Ap, Wp, b_f, b_b, gx);
    lstm_kernel<<<128, 576, 0, stream>>>(gx, Whp, seq_len, W_fc, featsF, featsB);
    crf_kernel<<<B_, 64, 0, stream>>>(featsF, featsB, b_fc, trans, tags, seq_len, nll);
    reduce_mean_kernel<<<1, 256, 0, stream>>>(nll, out);
}